// Round 16
// baseline (201.297 us; speedup 1.0000x reference)
//
#include <hip/hip_runtime.h>
#include <hip/hip_bf16.h>

#define Bb 8
#define Cch 256
#define Nn 2048
#define Mm 2048
#define KKEEP 1638
#define RANK 410   /* Nn - KKEEP, 0-indexed ascending rank of threshold */
#define HGROUPS 4
#define HPITCH 260 /* 4 sub-hists, 4-bank shift/group: cross-group conflict-free */
#define SPLITK2 2

typedef __hip_bfloat16 bf16;
typedef __attribute__((ext_vector_type(8))) short bf16x8;
typedef __attribute__((ext_vector_type(4))) float f32x4;
typedef unsigned int u32;
typedef unsigned short u16;

__device__ __forceinline__ void gload_lds16(const void* g, void* l) {
  __builtin_amdgcn_global_load_lds((const __attribute__((address_space(1))) u32*)g,
                                   (__attribute__((address_space(3))) u32*)l, 16, 0, 0);
}

// ------------- zero accumulators: bnsum(512) + sqx(16384) + sqt(16384) -----
__global__ __launch_bounds__(256) void zero_acc(float* p, int n) {
  int i = blockIdx.x * 256 + threadIdx.x;
  if (i < n) p[i] = 0.f;
}

// ------------- transpose + sumsq: out[b][n][c] = bf16(in[b][c][n]) ---------
// Raw (unnormalized) transpose; accumulates per-(b,n) sum of squares into
// sqacc via one atomicAdd per column per tile. Optionally emits raw bf16
// copy in original [b][c][n] layout (rawb). Norm applied in gemm1 epilogue.
__global__ __launch_bounds__(256) void transpose_sq(const float* __restrict__ in,
                                                    bf16* __restrict__ outp,
                                                    bf16* __restrict__ rawb,
                                                    float* __restrict__ sqacc) {
  __shared__ float tile[32][33];
  __shared__ float sqr[8][33];
  int b = blockIdx.z;
  int n0 = blockIdx.x * 32, c0 = blockIdx.y * 32;
  int tx = threadIdx.x, ty = threadIdx.y;
  const float* src = in + (size_t)b * Cch * Nn;
  float partial = 0.f;
  #pragma unroll
  for (int i = 0; i < 32; i += 8) {
    float v = src[(size_t)(c0 + ty + i) * Nn + n0 + tx];
    tile[ty + i][tx] = v;
    partial += v * v;
    if (rawb) rawb[(size_t)b * Cch * Nn + (size_t)(c0 + ty + i) * Nn + n0 + tx] = __float2bfloat16(v);
  }
  sqr[ty][tx] = partial;
  __syncthreads();
  bf16* dst = outp + (size_t)b * Nn * Cch;
  #pragma unroll
  for (int i = 0; i < 32; i += 8) {
    int n = n0 + ty + i;
    dst[(size_t)n * Cch + c0 + tx] = __float2bfloat16(tile[tx][ty + i]);
  }
  if (ty == 0) {
    float s = 0.f;
    #pragma unroll
    for (int yy = 0; yy < 8; yy++) s += sqr[yy][tx];
    atomicAdd(&sqacc[(b << 11) + n0 + tx], s);
  }
}

// ------------- finalize: inv = 1/max(sqrt(sumsq), 1e-12), in place ---------
__global__ __launch_bounds__(256) void inv_finalize(float* p, int n) {
  int i = blockIdx.x * 256 + threadIdx.x;
  if (i < n) p[i] = 1.f / fmaxf(sqrtf(p[i]), 1e-12f);
}

// ------------- gemm1: E = bf16(exp(acc * invt[m] * invx[n])) ---------------
// Raw-input GEMM; per-column normalization (cosine) applied in the epilogue
// (f32, once per output element instead of once per input element), then
// exp fused (monotone -> downstream top-k on E == top-k on S).
__global__ __launch_bounds__(256) void gemm_bt1(const bf16* __restrict__ A,
                                                const bf16* __restrict__ Bt,
                                                const float* __restrict__ invA,
                                                const float* __restrict__ invB,
                                                bf16* __restrict__ Cout,
                                                int Mrows, int Ncols, int K) {
  __shared__ bf16 aT[128 * 32];
  __shared__ bf16 bT[128 * 32];
  const int b = blockIdx.z;
  const int m0 = blockIdx.x * 128;
  const int n0 = blockIdx.y * 128;
  const bf16* Ab = A + (size_t)b * Mrows * K;
  const bf16* Bbp = Bt + (size_t)b * Ncols * K;
  const int tid = threadIdx.x;
  const int lane = tid & 63;
  const int wave = tid >> 6;
  const int wr = wave >> 1, wc = wave & 1;

  f32x4 acc[4][4];
  #pragma unroll
  for (int i = 0; i < 4; i++)
    #pragma unroll
    for (int j = 0; j < 4; j++) acc[i][j] = (f32x4){0.f, 0.f, 0.f, 0.f};

  const int srow = tid >> 2;
  const int scol = (tid & 3) * 8;
  const bf16* gA0 = Ab + (size_t)(m0 + srow) * K + scol;
  const bf16* gB0 = Bbp + (size_t)(n0 + srow) * K + scol;
  bf16* lA = aT + wave * 512;   // wave-uniform LDS base (lane*16B auto-added)
  bf16* lB = bT + wave * 512;

  const int fm = lane & 15;
  const int kb = (lane >> 4) * 8;

  for (int kt = 0; kt < K; kt += 32) {
    gload_lds16(gA0 + kt, lA);
    gload_lds16(gA0 + (size_t)64 * K + kt, lA + 2048);
    gload_lds16(gB0 + kt, lB);
    gload_lds16(gB0 + (size_t)64 * K + kt, lB + 2048);
    __syncthreads();
    bf16x8 af[4], bf_[4];
    #pragma unroll
    for (int mf = 0; mf < 4; mf++)
      af[mf] = *(const bf16x8*)&aT[(wr * 64 + mf * 16 + fm) * 32 + kb];
    #pragma unroll
    for (int nf = 0; nf < 4; nf++)
      bf_[nf] = *(const bf16x8*)&bT[(wc * 64 + nf * 16 + fm) * 32 + kb];
    #pragma unroll
    for (int mf = 0; mf < 4; mf++)
      #pragma unroll
      for (int nf = 0; nf < 4; nf++)
        acc[mf][nf] = __builtin_amdgcn_mfma_f32_16x16x32_bf16(af[mf], bf_[nf], acc[mf][nf], 0, 0, 0);
    __syncthreads();
  }

  const int orow = (lane >> 4) * 4;
  const int ocol = lane & 15;
  bf16* Cb = Cout + (size_t)b * Mrows * Ncols;
  float ix[4];
  #pragma unroll
  for (int nf = 0; nf < 4; nf++)
    ix[nf] = invB[(size_t)b * Ncols + n0 + wc * 64 + nf * 16 + ocol];
  #pragma unroll
  for (int mf = 0; mf < 4; mf++)
    #pragma unroll
    for (int r = 0; r < 4; r++) {
      int gm = m0 + wr * 64 + mf * 16 + orow + r;
      float it = invA[(size_t)b * Mrows + gm];
      #pragma unroll
      for (int nf = 0; nf < 4; nf++) {
        int gn = n0 + wc * 64 + nf * 16 + ocol;
        Cb[(size_t)gm * Ncols + gn] = __float2bfloat16(__expf(acc[mf][nf][r] * it * ix[nf]));
      }
    }
}

// ---- wave-level inclusive scan over 64 lanes ------------------------------
__device__ __forceinline__ u32 wave_incl_scan(u32 v, int lane) {
  #pragma unroll
  for (int off = 1; off < 64; off <<= 1) {
    u32 t = __shfl_up(v, off, 64);
    if (lane >= off) v += t;
  }
  return v;
}

// ------------- per-row top-k MASK over E = exp(S), in place ---------------
// ONE WAVE PER ROW. Pure-integer select on the 10-bit biased key
// v = clamp(u - 0x3E00, 0, 0x3FF) (monotone in E). Radix: pass1 v>>2,
// pass2 v&3. Masked write = u16 select. rowinv[row] = 1/sum(E).
__global__ __launch_bounds__(256) void row_topk_mask(bf16* __restrict__ S,
                                                     float* __restrict__ rowinv) {
  const int lane = threadIdx.x & 63;
  const int wv = threadIdx.x >> 6;                 // 0..3
  const int rowIdx = blockIdx.x * 4 + wv;
  bf16* row = S + (size_t)rowIdx * Nn;
  __shared__ u32 hist_s[4][HGROUPS * HPITCH];      // 4 x 4160B
  u32* hist = hist_s[wv];                          // wave-private
  u32* myhist = hist + (lane & (HGROUPS - 1)) * HPITCH;

  // ---- load: slot k holds global elems k*512 + lane*8 .. +7 ----
  uint4 rw[4];
  #pragma unroll
  for (int k = 0; k < 4; k++) rw[k] = ((const uint4*)row)[k * 64 + lane];

  u16 kv[32];
  float se = 0.f;
  #pragma unroll
  for (int k = 0; k < 4; k++) {
    u32 wd[4] = {rw[k].x, rw[k].y, rw[k].z, rw[k].w};
    #pragma unroll
    for (int j = 0; j < 4; j++) {
      u16 a = (u16)(wd[j] & 0xFFFF), b = (u16)(wd[j] >> 16);
      int i0 = k * 8 + 2 * j;
      int va = (int)a - 0x3E00; va = va < 0 ? 0 : (va > 0x3FF ? 0x3FF : va);
      int vb = (int)b - 0x3E00; vb = vb < 0 ? 0 : (vb > 0x3FF ? 0x3FF : vb);
      kv[i0] = (u16)va; kv[i0 + 1] = (u16)vb;
      u32 ba = ((u32)a) << 16, bb = ((u32)b) << 16;
      float fa, fb; __builtin_memcpy(&fa, &ba, 4); __builtin_memcpy(&fb, &bb, 4);
      se += fa + fb;                               // sum of E (denominator)
    }
  }
  #pragma unroll
  for (int off = 32; off > 0; off >>= 1) se += __shfl_xor(se, off, 64);
  if (lane == 0) rowinv[rowIdx] = 1.f / se;

  // ---- radix pass 1: histogram of v>>2 ----
  #pragma unroll
  for (int i = 0; i < 16; i++) hist[i * 64 + lane] = 0;
  if (lane < HGROUPS * HPITCH - 1024) hist[1024 + lane] = 0;
  __threadfence_block();
  #pragma unroll
  for (int i = 0; i < 32; i++) atomicAdd(&myhist[kv[i] >> 2], 1u);
  __threadfence_block();
  u32 h[4], c[4];
  h[0] = h[1] = h[2] = h[3] = 0;
  #pragma unroll
  for (int gg = 0; gg < HGROUPS; gg++) {
    uint4 v = *(const uint4*)&hist[gg * HPITCH + lane * 4];
    h[0] += v.x; h[1] += v.y; h[2] += v.z; h[3] += v.w;
  }
  c[0] = h[0]; c[1] = c[0] + h[1]; c[2] = c[1] + h[2]; c[3] = c[2] + h[3];
  u32 inclTot = wave_incl_scan(c[3], lane);
  u32 pre = inclTot - c[3];                         // exclusive prefix of my 4 bins
  u32 binsel = 0xFFFFFFFFu, belowv = 0;
  #pragma unroll
  for (int i = 0; i < 4; i++) {
    u32 incl = pre + c[i];
    if (incl > (u32)RANK && incl - h[i] <= (u32)RANK) { binsel = lane * 4 + i; belowv = incl - h[i]; }
  }
  unsigned long long mk = __ballot(binsel != 0xFFFFFFFFu);
  int src = __ffsll(mk) - 1;
  u32 b1 = __shfl(binsel, src, 64);
  u32 below = __shfl(belowv, src, 64);

  // ---- radix pass 2: v&3 among keys with v>>2 == b1 ----
  #pragma unroll
  for (int i = 0; i < 16; i++) hist[i * 64 + lane] = 0;
  if (lane < HGROUPS * HPITCH - 1024) hist[1024 + lane] = 0;
  __threadfence_block();
  #pragma unroll
  for (int i = 0; i < 32; i++)
    if ((u32)(kv[i] >> 2) == b1) atomicAdd(&myhist[kv[i] & 3], 1u);
  __threadfence_block();
  h[0] = h[1] = h[2] = h[3] = 0;
  #pragma unroll
  for (int gg = 0; gg < HGROUPS; gg++) {
    uint4 v = *(const uint4*)&hist[gg * HPITCH + lane * 4];
    h[0] += v.x; h[1] += v.y; h[2] += v.z; h[3] += v.w;
  }
  c[0] = h[0]; c[1] = c[0] + h[1]; c[2] = c[1] + h[2]; c[3] = c[2] + h[3];
  inclTot = wave_incl_scan(c[3], lane);
  pre = inclTot - c[3];
  binsel = 0xFFFFFFFFu; u32 totv = 0;
  #pragma unroll
  for (int i = 0; i < 4; i++) {
    u32 incl = below + pre + c[i];
    if (incl > (u32)RANK && incl - h[i] <= (u32)RANK) { binsel = lane * 4 + i; totv = incl; }
  }
  mk = __ballot(binsel != 0xFFFFFFFFu);
  src = __ffsll(mk) - 1;
  u32 lowb = __shfl(binsel, src, 64);               // 0..3 (lane 0's bins)
  u32 totalLE = __shfl(totv, src, 64);              // #keys <= tkey
  u16 tkey = (u16)((b1 << 2) | lowb);
  int keepEq = KKEEP - (Nn - (int)totalLE);         // ties kept, lowest global index first

  // ---- tie ordering: global idx = k*512 + lane*8 + j ----
  int eqk[4];
  #pragma unroll
  for (int k = 0; k < 4; k++) {
    int c2 = 0;
    #pragma unroll
    for (int j = 0; j < 8; j++) c2 += (kv[k * 8 + j] == tkey);
    eqk[k] = c2;
  }
  int eqbase[4]; int running = 0;
  #pragma unroll
  for (int k = 0; k < 4; k++) {
    u32 inclL = wave_incl_scan((u32)eqk[k], lane);
    int waveTot = __shfl((int)inclL, 63, 64);
    eqbase[k] = running + (int)inclL - eqk[k];
    running += waveTot;
  }

  // ---- masked write: keep iff v > tkey, or v == tkey and order < keepEq ---
  #pragma unroll
  for (int k = 0; k < 4; k++) {
    int eqs = eqbase[k];
    u32 wd[4] = {rw[k].x, rw[k].y, rw[k].z, rw[k].w};
    u32 od[4];
    #pragma unroll
    for (int j = 0; j < 4; j++) {
      u16 a = (u16)(wd[j] & 0xFFFF), b = (u16)(wd[j] >> 16);
      int i0 = k * 8 + 2 * j;
      u16 o0 = 0, o1 = 0;
      if (kv[i0] > tkey) o0 = a;
      else if (kv[i0] == tkey) { if (eqs < keepEq) o0 = a; eqs++; }
      if (kv[i0 + 1] > tkey) o1 = b;
      else if (kv[i0 + 1] == tkey) { if (eqs < keepEq) o1 = b; eqs++; }
      od[j] = (u32)o0 | ((u32)o1 << 16);
    }
    uint4 outv = {od[0], od[1], od[2], od[3]};
    ((uint4*)row)[k * 64 + lane] = outv;
  }
}

// ------------- REGISTER-DIRECT wave gemm2: part = xb * Emask^T -------------
// No LDS at all. Each lane loads its MFMA fragments straight from global:
// a 64-lane bf16x8 fragment load covers 16 rows x 64 contiguous bytes =
// 16 full cache lines (fully utilized). Removes the gload_lds->vmcnt(0)->
// ds_read critical path AND all LDS bank conflicts; the compiler emits
// per-fragment waits (no 6-load convoy). Hand 2-deep register pipeline
// (two named fragment sets, unroll-by-2) keeps 12 loads in flight/wave.
// __launch_bounds__(256,4) caps VGPR at 128 -> 4 waves/SIMD (grid gives 4
// blocks/CU). Split-K=2, bf16 partials, XCD pinning via blockIdx.x=batch.
__global__ __launch_bounds__(256, 4) void gemm2_wave(const bf16* __restrict__ A,
                                                     const bf16* __restrict__ Bt,
                                                     bf16* __restrict__ part) {
  constexpr int KS = Nn / SPLITK2;           // 1024 K per slice
  constexpr int NT = KS / 32;                // 32 steps
  constexpr int numTiles = (Cch / 128) * (Mm / 64);   // 64
  const int b = blockIdx.x;                  // XCD = dispatch_id % 8 = batch
  int yy = blockIdx.y;
  int tile = yy % numTiles, ks = yy / numTiles;
  int m0 = (tile % (Cch / 128)) * 128;       // m fastest: siblings adjacent
  int n0 = (tile / (Cch / 128)) * 64;
  const int lane = threadIdx.x & 63;
  const int w = threadIdx.x >> 6;
  const int fm = lane & 15;
  const int kb = (lane >> 4) * 8;
  const int kBeg = ks * KS;
  const bf16* pA = A + (size_t)b * Cch * Nn + (size_t)(m0 + w * 32 + fm) * Nn + kBeg + kb;
  const bf16* pB = Bt + (size_t)b * Mm * Nn + (size_t)(n0 + fm) * Nn + kBeg + kb;

  f32x4 acc[2][4];
  #pragma unroll
  for (int i = 0; i < 2; i++)
    #pragma unroll
    for (int j = 0; j < 4; j++) acc[i][j] = (f32x4){0.f, 0.f, 0.f, 0.f};

  bf16x8 a0[2], b0[4], a1[2], b1[4];
#define LDSET(aa, bb, kt)                                                     \
  {                                                                           \
    _Pragma("unroll")                                                         \
    for (int mf = 0; mf < 2; mf++)                                            \
      aa[mf] = *(const bf16x8*)(pA + (size_t)(mf * 16) * Nn + (kt));          \
    _Pragma("unroll")                                                         \
    for (int nf = 0; nf < 4; nf++)                                            \
      bb[nf] = *(const bf16x8*)(pB + (size_t)(nf * 16) * Nn + (kt));          \
  }
#define MMSET(aa, bb)                                                         \
  {                                                                           \
    _Pragma("unroll")                                                         \
    for (int mf = 0; mf < 2; mf++)                                            \
      _Pragma("unroll")                                                       \
      for (int nf = 0; nf < 4; nf++)                                          \
        acc[mf][nf] = __builtin_amdgcn_mfma_f32_16x16x32_bf16(aa[mf], bb[nf], acc[mf][nf], 0, 0, 0); \
  }

  LDSET(a0, b0, 0);
  for (int t = 0; t < NT; t += 2) {
    LDSET(a1, b1, (t + 1) * 32);             // t+1 < NT always (NT even)
    MMSET(a0, b0);
    if (t + 2 < NT) LDSET(a0, b0, (t + 2) * 32);
    MMSET(a1, b1);
  }
#undef LDSET
#undef MMSET

  const int orow = (lane >> 4) * 4;
  const int ocol = lane & 15;
  bf16* Pb = part + ((size_t)ks * Bb + b) * Cch * Mm;
  #pragma unroll
  for (int mf = 0; mf < 2; mf++)
    #pragma unroll
    for (int nf = 0; nf < 4; nf++)
      #pragma unroll
      for (int r = 0; r < 4; r++) {
        int gm = m0 + w * 32 + mf * 16 + orow + r;
        int gn = n0 + nf * 16 + ocol;
        Pb[(size_t)gm * Mm + gn] = __float2bfloat16(acc[mf][nf][r]);
      }
}

// ------------- combine split-K bf16 partials: *inv[m], leaky, BN, out ------
__global__ __launch_bounds__(256) void combine_bn(const bf16* __restrict__ part,
                                                  const float* __restrict__ rowinv,
                                                  float* __restrict__ outp,
                                                  float* __restrict__ bnsum) {
  int bc = blockIdx.x;                       // b*Cch + c
  int b = bc >> 8;
  int tid = threadIdx.x;
  size_t sl = (size_t)Bb * Cch * Mm;
  uint4 a0 = ((const uint4*)(part + (size_t)bc * Mm))[tid];        // 8 bf16
  uint4 a1 = ((const uint4*)(part + sl + (size_t)bc * Mm))[tid];
  const float4* iv = (const float4*)(rowinv + (size_t)b * Mm);
  float4 w0 = iv[tid * 2], w1 = iv[tid * 2 + 1];
  float v[8];
  #pragma unroll
  for (int j = 0; j < 4; j++) {
    u32 x0 = ((const u32*)&a0)[j], x1 = ((const u32*)&a1)[j];
    u32 lo0 = x0 << 16, hi0 = x0 & 0xFFFF0000u;
    u32 lo1 = x1 << 16, hi1 = x1 & 0xFFFF0000u;
    float f0, f1, g0, g1;
    __builtin_memcpy(&f0, &lo0, 4); __builtin_memcpy(&f1, &hi0, 4);
    __builtin_memcpy(&g0, &lo1, 4); __builtin_memcpy(&g1, &hi1, 4);
    v[2 * j] = f0 + g0; v[2 * j + 1] = f1 + g1;
  }
  v[0] *= w0.x; v[1] *= w0.y; v[2] *= w0.z; v[3] *= w0.w;
  v[4] *= w1.x; v[5] *= w1.y; v[6] *= w1.z; v[7] *= w1.w;
  float s = 0.f, ss = 0.f;
  #pragma unroll
  for (int j = 0; j < 8; j++) {
    float y = v[j];
    y = y >= 0.f ? y : 0.01f * y;
    v[j] = y;
    s += y; ss += y * y;
  }
  float4* po = (float4*)(outp + (size_t)bc * Mm);
  po[tid * 2]     = make_float4(v[0], v[1], v[2], v[3]);
  po[tid * 2 + 1] = make_float4(v[4], v[5], v[6], v[7]);
  __shared__ float r1[256], r2[256];
  r1[tid] = s; r2[tid] = ss; __syncthreads();
  for (int k = 128; k > 0; k >>= 1) {
    if (tid < k) { r1[tid] += r1[tid + k]; r2[tid] += r2[tid + k]; }
    __syncthreads();
  }
  if (tid == 0) {
    int c = bc & (Cch - 1);
    atomicAdd(&bnsum[c], r1[0]);
    atomicAdd(&bnsum[Cch + c], r2[0]);
  }
}

// ------------- BN finalize: scale/shift per channel ------------------------
__global__ __launch_bounds__(256) void bn_finalize(const float* __restrict__ bnsum,
                                                   const float* __restrict__ bnw,
                                                   const float* __restrict__ bnb,
                                                   float* __restrict__ scsh) {
  int c = threadIdx.x;
  float cnt = (float)(Bb * Mm);
  float mean = bnsum[c] / cnt;
  float var = bnsum[Cch + c] / cnt - mean * mean;
  float scale = bnw[c] / sqrtf(var + 1e-5f);
  scsh[c * 2] = scale;
  scsh[c * 2 + 1] = bnb[c] - mean * scale;
}

// ------------- final: out = (y*scale+shift)*gamma + tg --------------------
__global__ __launch_bounds__(256) void final_kernel(float* io, const float* __restrict__ tg,
                                                    const float* __restrict__ scsh,
                                                    const float* __restrict__ gamma) {
  size_t n4 = (size_t)Bb * Cch * Mm / 4;
  float g = gamma[0];
  size_t stride = (size_t)gridDim.x * 256;
  for (size_t i = (size_t)blockIdx.x * 256 + threadIdx.x; i < n4; i += stride) {
    int c = (int)((i * 4 / Mm) % Cch);
    float4 v = ((const float4*)io)[i];
    float4 t = ((const float4*)tg)[i];
    float sc = scsh[c * 2], sh = scsh[c * 2 + 1];
    v.x = (v.x * sc + sh) * g + t.x;
    v.y = (v.y * sc + sh) * g + t.y;
    v.z = (v.z * sc + sh) * g + t.z;
    v.w = (v.w * sc + sh) * g + t.w;
    ((float4*)io)[i] = v;
  }
}

extern "C" void kernel_launch(void* const* d_in, const int* in_sizes, int n_in,
                              void* d_out, int out_size, void* d_ws, size_t ws_size,
                              hipStream_t stream) {
  (void)in_sizes; (void)n_in; (void)out_size; (void)ws_size;
  const float* x   = (const float*)d_in[0];
  const float* tg  = (const float*)d_in[1];
  const float* gamma = (const float*)d_in[2];
  const float* bnw = (const float*)d_in[3];
  const float* bnb = (const float*)d_in[4];
  float* out = (float*)d_out;

  char* ws = (char*)d_ws;
  bf16* xnT  = (bf16*)ws; ws += (size_t)Bb * Nn * Cch * 2;
  bf16* tgnT = (bf16*)ws; ws += (size_t)Bb * Mm * Cch * 2;
  bf16* xb   = (bf16*)ws; ws += (size_t)Bb * Cch * Nn * 2;
  bf16* S    = (bf16*)ws; ws += (size_t)Bb * Mm * Nn * 2;   // holds E = exp(S)
  bf16* part = (bf16*)ws; ws += (size_t)SPLITK2 * Bb * Cch * Mm * 2;
  float* rowinv = (float*)ws; ws += (size_t)Bb * Mm * 4;
  // contiguous accumulator block (zeroed each launch):
  float* bnsum = (float*)ws; ws += (size_t)2 * Cch * 4;
  float* invx  = (float*)ws; ws += (size_t)Bb * Nn * 4;     // sumsq -> inv
  float* invt  = (float*)ws; ws += (size_t)Bb * Mm * 4;
  float* scsh  = (float*)ws; ws += (size_t)Cch * 2 * 4;
  const int accN = 2 * Cch + Bb * Nn + Bb * Mm;             // 33280 floats

  zero_acc<<<(accN + 255) / 256, 256, 0, stream>>>(bnsum, accN);
  transpose_sq<<<dim3(Nn / 32, Cch / 32, Bb), dim3(32, 8), 0, stream>>>(x, xnT, xb, invx);
  transpose_sq<<<dim3(Mm / 32, Cch / 32, Bb), dim3(32, 8), 0, stream>>>(tg, tgnT, nullptr, invt);
  inv_finalize<<<(Bb * (Nn + Mm) + 255) / 256, 256, 0, stream>>>(invx, Bb * (Nn + Mm));
  // E[b][m][n] = exp( dot(tg_m, x_n) * invt[m] * invx[n] )
  gemm_bt1<<<dim3(Mm / 128, Nn / 128, Bb), 256, 0, stream>>>(tgnT, xnT, invt, invx, S, Mm, Nn, Cch);
  // in-place top-k mask on E + rowinv = 1/sum(E)
  row_topk_mask<<<Bb * Mm / 4, 256, 0, stream>>>(S, rowinv);
  // part[b][c][m] = sum_n xb[b][c][n] * Emask[b][m][n]  (register-direct)
  gemm2_wave<<<dim3(Bb, (Cch / 128) * (Mm / 64) * SPLITK2, 1), 256, 0, stream>>>(xb, S, part);
  combine_bn<<<Bb * Cch, 256, 0, stream>>>(part, rowinv, out, bnsum);
  bn_finalize<<<1, 256, 0, stream>>>(bnsum, bnw, bnb, scsh);
  final_kernel<<<2048, 256, 0, stream>>>(out, tg, scsh, gamma);
}

// Round 17
// 157.038 us; speedup vs baseline: 1.2818x; 1.2818x over previous
//
#include <hip/hip_runtime.h>
#include <hip/hip_bf16.h>

#define Bb 8
#define Cch 256
#define Nn 2048
#define Mm 2048
#define KKEEP 1638
#define RANK 410   /* Nn - KKEEP, 0-indexed ascending rank of threshold */
#define HGROUPS 4
#define HPITCH 260 /* 4 sub-hists, 4-bank shift/group: cross-group conflict-free */
#define SPLITK 4

typedef __hip_bfloat16 bf16;
typedef __attribute__((ext_vector_type(8))) short bf16x8;
typedef __attribute__((ext_vector_type(4))) float f32x4;
typedef unsigned int u32;
typedef unsigned short u16;

__device__ __forceinline__ void gload_lds16(const void* g, void* l) {
  __builtin_amdgcn_global_load_lds((const __attribute__((address_space(1))) u32*)g,
                                   (__attribute__((address_space(3))) u32*)l, 16, 0, 0);
}

// ------------- zero accumulators: bnsum(512) + sqx(16384) + sqt(16384) -----
__global__ __launch_bounds__(256) void zero_acc(float* p, int n) {
  int i = blockIdx.x * 256 + threadIdx.x;
  if (i < n) p[i] = 0.f;
}

// ------------- transpose + sumsq: out[b][n][c] = bf16(in[b][c][n]) ---------
// Raw (unnormalized) transpose; accumulates per-(b,n) sum of squares into
// sqacc via one atomicAdd per column per tile. Optionally emits raw bf16
// copy in original [b][c][n] layout (rawb). Norm applied in gemm1 epilogue.
__global__ __launch_bounds__(256) void transpose_sq(const float* __restrict__ in,
                                                    bf16* __restrict__ outp,
                                                    bf16* __restrict__ rawb,
                                                    float* __restrict__ sqacc) {
  __shared__ float tile[32][33];
  __shared__ float sqr[8][33];
  int b = blockIdx.z;
  int n0 = blockIdx.x * 32, c0 = blockIdx.y * 32;
  int tx = threadIdx.x, ty = threadIdx.y;
  const float* src = in + (size_t)b * Cch * Nn;
  float partial = 0.f;
  #pragma unroll
  for (int i = 0; i < 32; i += 8) {
    float v = src[(size_t)(c0 + ty + i) * Nn + n0 + tx];
    tile[ty + i][tx] = v;
    partial += v * v;
    if (rawb) rawb[(size_t)b * Cch * Nn + (size_t)(c0 + ty + i) * Nn + n0 + tx] = __float2bfloat16(v);
  }
  sqr[ty][tx] = partial;
  __syncthreads();
  bf16* dst = outp + (size_t)b * Nn * Cch;
  #pragma unroll
  for (int i = 0; i < 32; i += 8) {
    int n = n0 + ty + i;
    dst[(size_t)n * Cch + c0 + tx] = __float2bfloat16(tile[tx][ty + i]);
  }
  if (ty == 0) {
    float s = 0.f;
    #pragma unroll
    for (int yy = 0; yy < 8; yy++) s += sqr[yy][tx];
    atomicAdd(&sqacc[(b << 11) + n0 + tx], s);
  }
}

// ------------- finalize: inv = 1/max(sqrt(sumsq), 1e-12), in place ---------
__global__ __launch_bounds__(256) void inv_finalize(float* p, int n) {
  int i = blockIdx.x * 256 + threadIdx.x;
  if (i < n) p[i] = 1.f / fmaxf(sqrtf(p[i]), 1e-12f);
}

// ------------- gemm1: E = bf16(exp(acc * invt[m] * invx[n])) ---------------
// Raw-input GEMM; per-column normalization (cosine) applied in the epilogue
// (f32, once per output element instead of once per input element), then
// exp fused (monotone -> downstream top-k on E == top-k on S).
__global__ __launch_bounds__(256) void gemm_bt1(const bf16* __restrict__ A,
                                                const bf16* __restrict__ Bt,
                                                const float* __restrict__ invA,
                                                const float* __restrict__ invB,
                                                bf16* __restrict__ Cout,
                                                int Mrows, int Ncols, int K) {
  __shared__ bf16 aT[128 * 32];
  __shared__ bf16 bT[128 * 32];
  const int b = blockIdx.z;
  const int m0 = blockIdx.x * 128;
  const int n0 = blockIdx.y * 128;
  const bf16* Ab = A + (size_t)b * Mrows * K;
  const bf16* Bbp = Bt + (size_t)b * Ncols * K;
  const int tid = threadIdx.x;
  const int lane = tid & 63;
  const int wave = tid >> 6;
  const int wr = wave >> 1, wc = wave & 1;

  f32x4 acc[4][4];
  #pragma unroll
  for (int i = 0; i < 4; i++)
    #pragma unroll
    for (int j = 0; j < 4; j++) acc[i][j] = (f32x4){0.f, 0.f, 0.f, 0.f};

  const int srow = tid >> 2;
  const int scol = (tid & 3) * 8;
  const bf16* gA0 = Ab + (size_t)(m0 + srow) * K + scol;
  const bf16* gB0 = Bbp + (size_t)(n0 + srow) * K + scol;
  bf16* lA = aT + wave * 512;   // wave-uniform LDS base (lane*16B auto-added)
  bf16* lB = bT + wave * 512;

  const int fm = lane & 15;
  const int kb = (lane >> 4) * 8;

  for (int kt = 0; kt < K; kt += 32) {
    gload_lds16(gA0 + kt, lA);
    gload_lds16(gA0 + (size_t)64 * K + kt, lA + 2048);
    gload_lds16(gB0 + kt, lB);
    gload_lds16(gB0 + (size_t)64 * K + kt, lB + 2048);
    __syncthreads();
    bf16x8 af[4], bf_[4];
    #pragma unroll
    for (int mf = 0; mf < 4; mf++)
      af[mf] = *(const bf16x8*)&aT[(wr * 64 + mf * 16 + fm) * 32 + kb];
    #pragma unroll
    for (int nf = 0; nf < 4; nf++)
      bf_[nf] = *(const bf16x8*)&bT[(wc * 64 + nf * 16 + fm) * 32 + kb];
    #pragma unroll
    for (int mf = 0; mf < 4; mf++)
      #pragma unroll
      for (int nf = 0; nf < 4; nf++)
        acc[mf][nf] = __builtin_amdgcn_mfma_f32_16x16x32_bf16(af[mf], bf_[nf], acc[mf][nf], 0, 0, 0);
    __syncthreads();
  }

  const int orow = (lane >> 4) * 4;
  const int ocol = lane & 15;
  bf16* Cb = Cout + (size_t)b * Mrows * Ncols;
  float ix[4];
  #pragma unroll
  for (int nf = 0; nf < 4; nf++)
    ix[nf] = invB[(size_t)b * Ncols + n0 + wc * 64 + nf * 16 + ocol];
  #pragma unroll
  for (int mf = 0; mf < 4; mf++)
    #pragma unroll
    for (int r = 0; r < 4; r++) {
      int gm = m0 + wr * 64 + mf * 16 + orow + r;
      float it = invA[(size_t)b * Mrows + gm];
      #pragma unroll
      for (int nf = 0; nf < 4; nf++) {
        int gn = n0 + wc * 64 + nf * 16 + ocol;
        Cb[(size_t)gm * Ncols + gn] = __float2bfloat16(__expf(acc[mf][nf][r] * it * ix[nf]));
      }
    }
}

// ---- wave-level inclusive scan over 64 lanes ------------------------------
__device__ __forceinline__ u32 wave_incl_scan(u32 v, int lane) {
  #pragma unroll
  for (int off = 1; off < 64; off <<= 1) {
    u32 t = __shfl_up(v, off, 64);
    if (lane >= off) v += t;
  }
  return v;
}

// ------------- per-row top-k MASK over E = exp(S), in place ---------------
// ONE WAVE PER ROW. Pure-integer select on the 10-bit biased key
// v = clamp(u - 0x3E00, 0, 0x3FF) (monotone in E). Radix: pass1 v>>2,
// pass2 v&3. Masked write = u16 select. rowinv[row] = 1/sum(E).
__global__ __launch_bounds__(256) void row_topk_mask(bf16* __restrict__ S,
                                                     float* __restrict__ rowinv) {
  const int lane = threadIdx.x & 63;
  const int wv = threadIdx.x >> 6;                 // 0..3
  const int rowIdx = blockIdx.x * 4 + wv;
  bf16* row = S + (size_t)rowIdx * Nn;
  __shared__ u32 hist_s[4][HGROUPS * HPITCH];      // 4 x 4160B
  u32* hist = hist_s[wv];                          // wave-private
  u32* myhist = hist + (lane & (HGROUPS - 1)) * HPITCH;

  // ---- load: slot k holds global elems k*512 + lane*8 .. +7 ----
  uint4 rw[4];
  #pragma unroll
  for (int k = 0; k < 4; k++) rw[k] = ((const uint4*)row)[k * 64 + lane];

  u16 kv[32];
  float se = 0.f;
  #pragma unroll
  for (int k = 0; k < 4; k++) {
    u32 wd[4] = {rw[k].x, rw[k].y, rw[k].z, rw[k].w};
    #pragma unroll
    for (int j = 0; j < 4; j++) {
      u16 a = (u16)(wd[j] & 0xFFFF), b = (u16)(wd[j] >> 16);
      int i0 = k * 8 + 2 * j;
      int va = (int)a - 0x3E00; va = va < 0 ? 0 : (va > 0x3FF ? 0x3FF : va);
      int vb = (int)b - 0x3E00; vb = vb < 0 ? 0 : (vb > 0x3FF ? 0x3FF : vb);
      kv[i0] = (u16)va; kv[i0 + 1] = (u16)vb;
      u32 ba = ((u32)a) << 16, bb = ((u32)b) << 16;
      float fa, fb; __builtin_memcpy(&fa, &ba, 4); __builtin_memcpy(&fb, &bb, 4);
      se += fa + fb;                               // sum of E (denominator)
    }
  }
  #pragma unroll
  for (int off = 32; off > 0; off >>= 1) se += __shfl_xor(se, off, 64);
  if (lane == 0) rowinv[rowIdx] = 1.f / se;

  // ---- radix pass 1: histogram of v>>2 ----
  #pragma unroll
  for (int i = 0; i < 16; i++) hist[i * 64 + lane] = 0;
  if (lane < HGROUPS * HPITCH - 1024) hist[1024 + lane] = 0;
  __threadfence_block();
  #pragma unroll
  for (int i = 0; i < 32; i++) atomicAdd(&myhist[kv[i] >> 2], 1u);
  __threadfence_block();
  u32 h[4], c[4];
  h[0] = h[1] = h[2] = h[3] = 0;
  #pragma unroll
  for (int gg = 0; gg < HGROUPS; gg++) {
    uint4 v = *(const uint4*)&hist[gg * HPITCH + lane * 4];
    h[0] += v.x; h[1] += v.y; h[2] += v.z; h[3] += v.w;
  }
  c[0] = h[0]; c[1] = c[0] + h[1]; c[2] = c[1] + h[2]; c[3] = c[2] + h[3];
  u32 inclTot = wave_incl_scan(c[3], lane);
  u32 pre = inclTot - c[3];                         // exclusive prefix of my 4 bins
  u32 binsel = 0xFFFFFFFFu, belowv = 0;
  #pragma unroll
  for (int i = 0; i < 4; i++) {
    u32 incl = pre + c[i];
    if (incl > (u32)RANK && incl - h[i] <= (u32)RANK) { binsel = lane * 4 + i; belowv = incl - h[i]; }
  }
  unsigned long long mk = __ballot(binsel != 0xFFFFFFFFu);
  int src = __ffsll(mk) - 1;
  u32 b1 = __shfl(binsel, src, 64);
  u32 below = __shfl(belowv, src, 64);

  // ---- radix pass 2: v&3 among keys with v>>2 == b1 ----
  #pragma unroll
  for (int i = 0; i < 16; i++) hist[i * 64 + lane] = 0;
  if (lane < HGROUPS * HPITCH - 1024) hist[1024 + lane] = 0;
  __threadfence_block();
  #pragma unroll
  for (int i = 0; i < 32; i++)
    if ((u32)(kv[i] >> 2) == b1) atomicAdd(&myhist[kv[i] & 3], 1u);
  __threadfence_block();
  h[0] = h[1] = h[2] = h[3] = 0;
  #pragma unroll
  for (int gg = 0; gg < HGROUPS; gg++) {
    uint4 v = *(const uint4*)&hist[gg * HPITCH + lane * 4];
    h[0] += v.x; h[1] += v.y; h[2] += v.z; h[3] += v.w;
  }
  c[0] = h[0]; c[1] = c[0] + h[1]; c[2] = c[1] + h[2]; c[3] = c[2] + h[3];
  inclTot = wave_incl_scan(c[3], lane);
  pre = inclTot - c[3];
  binsel = 0xFFFFFFFFu; u32 totv = 0;
  #pragma unroll
  for (int i = 0; i < 4; i++) {
    u32 incl = below + pre + c[i];
    if (incl > (u32)RANK && incl - h[i] <= (u32)RANK) { binsel = lane * 4 + i; totv = incl; }
  }
  mk = __ballot(binsel != 0xFFFFFFFFu);
  src = __ffsll(mk) - 1;
  u32 lowb = __shfl(binsel, src, 64);               // 0..3 (lane 0's bins)
  u32 totalLE = __shfl(totv, src, 64);              // #keys <= tkey
  u16 tkey = (u16)((b1 << 2) | lowb);
  int keepEq = KKEEP - (Nn - (int)totalLE);         // ties kept, lowest global index first

  // ---- tie ordering: global idx = k*512 + lane*8 + j ----
  int eqk[4];
  #pragma unroll
  for (int k = 0; k < 4; k++) {
    int c2 = 0;
    #pragma unroll
    for (int j = 0; j < 8; j++) c2 += (kv[k * 8 + j] == tkey);
    eqk[k] = c2;
  }
  int eqbase[4]; int running = 0;
  #pragma unroll
  for (int k = 0; k < 4; k++) {
    u32 inclL = wave_incl_scan((u32)eqk[k], lane);
    int waveTot = __shfl((int)inclL, 63, 64);
    eqbase[k] = running + (int)inclL - eqk[k];
    running += waveTot;
  }

  // ---- masked write: keep iff v > tkey, or v == tkey and order < keepEq ---
  #pragma unroll
  for (int k = 0; k < 4; k++) {
    int eqs = eqbase[k];
    u32 wd[4] = {rw[k].x, rw[k].y, rw[k].z, rw[k].w};
    u32 od[4];
    #pragma unroll
    for (int j = 0; j < 4; j++) {
      u16 a = (u16)(wd[j] & 0xFFFF), b = (u16)(wd[j] >> 16);
      int i0 = k * 8 + 2 * j;
      u16 o0 = 0, o1 = 0;
      if (kv[i0] > tkey) o0 = a;
      else if (kv[i0] == tkey) { if (eqs < keepEq) o0 = a; eqs++; }
      if (kv[i0 + 1] > tkey) o1 = b;
      else if (kv[i0 + 1] == tkey) { if (eqs < keepEq) o1 = b; eqs++; }
      od[j] = (u32)o0 | ((u32)o1 << 16);
    }
    uint4 outv = {od[0], od[1], od[2], od[3]};
    ((uint4*)row)[k * 64 + lane] = outv;
  }
}

// ------------- WAVE-ASYNC gemm2: part = xb * Emask^T, split-K partials -----
// r15's proven structure (r16's register-direct regressed 2x: compiler
// capped VGPR at 64 and serialized the fragment loads). Each wave owns an
// independent 32x64 output tile with PRIVATE LDS slices. Per K-step: 6x
// global_load_lds -> s_waitcnt vmcnt(0) (per-wave counter; no barrier) ->
// 8 MFMA. SPLITK=4: grid 2048 = 8 blocks/CU (was 4, grid-limited at 30%
// occupancy; LDS 24KB allows 6). bf16 partials; blockIdx.x = batch = XCD.
__global__ __launch_bounds__(256) void gemm2_wave(const bf16* __restrict__ A,
                                                  const bf16* __restrict__ Bt,
                                                  bf16* __restrict__ part) {
  constexpr int KS = Nn / SPLITK;            // 512 K per slice
  constexpr int NT = KS / 32;                // 16 steps
  constexpr int numTiles = (Cch / 128) * (Mm / 64);   // 64
  __shared__ bf16 aW[4][32 * 32];
  __shared__ bf16 bW[4][64 * 32];
  const int b = blockIdx.x;                  // XCD = dispatch_id % 8 = batch
  int yy = blockIdx.y;
  int tile = yy % numTiles, ks = yy / numTiles;
  int m0 = (tile % (Cch / 128)) * 128;       // m fastest: siblings adjacent
  int n0 = (tile / (Cch / 128)) * 64;
  const bf16* Ab = A + (size_t)b * Cch * Nn;
  const bf16* Bbp = Bt + (size_t)b * Mm * Nn;
  const int lane = threadIdx.x & 63;
  const int w = threadIdx.x >> 6;
  const int srow = lane >> 2;                // 16 rows per gload
  const int scol = (lane & 3) * 8;
  const int kBeg = ks * KS;
  const bf16* gA = Ab + (size_t)(m0 + w * 32 + srow) * Nn + kBeg + scol;
  const bf16* gB = Bbp + (size_t)(n0 + srow) * Nn + kBeg + scol;
  const int fm = lane & 15;
  const int kb = (lane >> 4) * 8;

  f32x4 acc[2][4];
  #pragma unroll
  for (int i = 0; i < 2; i++)
    #pragma unroll
    for (int j = 0; j < 4; j++) acc[i][j] = (f32x4){0.f, 0.f, 0.f, 0.f};

  bf16* lA = &aW[w][0];                      // wave-uniform LDS bases
  bf16* lB = &bW[w][0];

  for (int t = 0; t < NT; ++t) {
    int kt = t * 32;
    gload_lds16(gA + kt, lA);
    gload_lds16(gA + (size_t)16 * Nn + kt, lA + 16 * 32);
    #pragma unroll
    for (int i = 0; i < 4; i++)
      gload_lds16(gB + (size_t)(i * 16) * Nn + kt, lB + i * 16 * 32);
    asm volatile("s_waitcnt vmcnt(0)" ::: "memory");
    bf16x8 af[2], bf_[4];
    #pragma unroll
    for (int mf = 0; mf < 2; mf++)
      af[mf] = *(const bf16x8*)&aW[w][(mf * 16 + fm) * 32 + kb];
    #pragma unroll
    for (int nf = 0; nf < 4; nf++)
      bf_[nf] = *(const bf16x8*)&bW[w][(nf * 16 + fm) * 32 + kb];
    #pragma unroll
    for (int mf = 0; mf < 2; mf++)
      #pragma unroll
      for (int nf = 0; nf < 4; nf++)
        acc[mf][nf] = __builtin_amdgcn_mfma_f32_16x16x32_bf16(af[mf], bf_[nf], acc[mf][nf], 0, 0, 0);
  }

  const int orow = (lane >> 4) * 4;
  const int ocol = lane & 15;
  bf16* Pb = part + ((size_t)ks * Bb + b) * Cch * Mm;
  #pragma unroll
  for (int mf = 0; mf < 2; mf++)
    #pragma unroll
    for (int nf = 0; nf < 4; nf++)
      #pragma unroll
      for (int r = 0; r < 4; r++) {
        int gm = m0 + w * 32 + mf * 16 + orow + r;
        int gn = n0 + nf * 16 + ocol;
        Pb[(size_t)gm * Mm + gn] = __float2bfloat16(acc[mf][nf][r]);
      }
}

// ------------- combine split-K bf16 partials: *inv[m], leaky, BN, out ------
__global__ __launch_bounds__(256) void combine_bn(const bf16* __restrict__ part,
                                                  const float* __restrict__ rowinv,
                                                  float* __restrict__ outp,
                                                  float* __restrict__ bnsum) {
  int bc = blockIdx.x;                       // b*Cch + c
  int b = bc >> 8;
  int tid = threadIdx.x;
  size_t sl = (size_t)Bb * Cch * Mm;
  uint4 a[SPLITK];
  #pragma unroll
  for (int s = 0; s < SPLITK; s++)
    a[s] = ((const uint4*)(part + s * sl + (size_t)bc * Mm))[tid];
  const float4* iv = (const float4*)(rowinv + (size_t)b * Mm);
  float4 w0 = iv[tid * 2], w1 = iv[tid * 2 + 1];
  float v[8];
  #pragma unroll
  for (int j = 0; j < 4; j++) {
    float lo = 0.f, hi = 0.f;
    #pragma unroll
    for (int s = 0; s < SPLITK; s++) {
      u32 xw = ((const u32*)&a[s])[j];
      u32 lb = xw << 16, hb = xw & 0xFFFF0000u;
      float f0, f1; __builtin_memcpy(&f0, &lb, 4); __builtin_memcpy(&f1, &hb, 4);
      lo += f0; hi += f1;
    }
    v[2 * j] = lo; v[2 * j + 1] = hi;
  }
  v[0] *= w0.x; v[1] *= w0.y; v[2] *= w0.z; v[3] *= w0.w;
  v[4] *= w1.x; v[5] *= w1.y; v[6] *= w1.z; v[7] *= w1.w;
  float s = 0.f, ss = 0.f;
  #pragma unroll
  for (int j = 0; j < 8; j++) {
    float y = v[j];
    y = y >= 0.f ? y : 0.01f * y;
    v[j] = y;
    s += y; ss += y * y;
  }
  float4* po = (float4*)(outp + (size_t)bc * Mm);
  po[tid * 2]     = make_float4(v[0], v[1], v[2], v[3]);
  po[tid * 2 + 1] = make_float4(v[4], v[5], v[6], v[7]);
  __shared__ float r1[256], r2[256];
  r1[tid] = s; r2[tid] = ss; __syncthreads();
  for (int k = 128; k > 0; k >>= 1) {
    if (tid < k) { r1[tid] += r1[tid + k]; r2[tid] += r2[tid + k]; }
    __syncthreads();
  }
  if (tid == 0) {
    int c = bc & (Cch - 1);
    atomicAdd(&bnsum[c], r1[0]);
    atomicAdd(&bnsum[Cch + c], r2[0]);
  }
}

// ------------- BN finalize: scale/shift per channel ------------------------
__global__ __launch_bounds__(256) void bn_finalize(const float* __restrict__ bnsum,
                                                   const float* __restrict__ bnw,
                                                   const float* __restrict__ bnb,
                                                   float* __restrict__ scsh) {
  int c = threadIdx.x;
  float cnt = (float)(Bb * Mm);
  float mean = bnsum[c] / cnt;
  float var = bnsum[Cch + c] / cnt - mean * mean;
  float scale = bnw[c] / sqrtf(var + 1e-5f);
  scsh[c * 2] = scale;
  scsh[c * 2 + 1] = bnb[c] - mean * scale;
}

// ------------- final: out = (y*scale+shift)*gamma + tg --------------------
__global__ __launch_bounds__(256) void final_kernel(float* io, const float* __restrict__ tg,
                                                    const float* __restrict__ scsh,
                                                    const float* __restrict__ gamma) {
  size_t n4 = (size_t)Bb * Cch * Mm / 4;
  float g = gamma[0];
  size_t stride = (size_t)gridDim.x * 256;
  for (size_t i = (size_t)blockIdx.x * 256 + threadIdx.x; i < n4; i += stride) {
    int c = (int)((i * 4 / Mm) % Cch);
    float4 v = ((const float4*)io)[i];
    float4 t = ((const float4*)tg)[i];
    float sc = scsh[c * 2], sh = scsh[c * 2 + 1];
    v.x = (v.x * sc + sh) * g + t.x;
    v.y = (v.y * sc + sh) * g + t.y;
    v.z = (v.z * sc + sh) * g + t.z;
    v.w = (v.w * sc + sh) * g + t.w;
    ((float4*)io)[i] = v;
  }
}

extern "C" void kernel_launch(void* const* d_in, const int* in_sizes, int n_in,
                              void* d_out, int out_size, void* d_ws, size_t ws_size,
                              hipStream_t stream) {
  (void)in_sizes; (void)n_in; (void)out_size; (void)ws_size;
  const float* x   = (const float*)d_in[0];
  const float* tg  = (const float*)d_in[1];
  const float* gamma = (const float*)d_in[2];
  const float* bnw = (const float*)d_in[3];
  const float* bnb = (const float*)d_in[4];
  float* out = (float*)d_out;

  char* ws = (char*)d_ws;
  bf16* xnT  = (bf16*)ws; ws += (size_t)Bb * Nn * Cch * 2;
  bf16* tgnT = (bf16*)ws; ws += (size_t)Bb * Mm * Cch * 2;
  bf16* xb   = (bf16*)ws; ws += (size_t)Bb * Cch * Nn * 2;
  bf16* S    = (bf16*)ws; ws += (size_t)Bb * Mm * Nn * 2;   // holds E = exp(S)
  bf16* part = (bf16*)ws; ws += (size_t)SPLITK * Bb * Cch * Mm * 2;
  float* rowinv = (float*)ws; ws += (size_t)Bb * Mm * 4;
  // contiguous accumulator block (zeroed each launch):
  float* bnsum = (float*)ws; ws += (size_t)2 * Cch * 4;
  float* invx  = (float*)ws; ws += (size_t)Bb * Nn * 4;     // sumsq -> inv
  float* invt  = (float*)ws; ws += (size_t)Bb * Mm * 4;
  float* scsh  = (float*)ws; ws += (size_t)Cch * 2 * 4;
  const int accN = 2 * Cch + Bb * Nn + Bb * Mm;             // 33280 floats

  zero_acc<<<(accN + 255) / 256, 256, 0, stream>>>(bnsum, accN);
  transpose_sq<<<dim3(Nn / 32, Cch / 32, Bb), dim3(32, 8), 0, stream>>>(x, xnT, xb, invx);
  transpose_sq<<<dim3(Mm / 32, Cch / 32, Bb), dim3(32, 8), 0, stream>>>(tg, tgnT, nullptr, invt);
  inv_finalize<<<(Bb * (Nn + Mm) + 255) / 256, 256, 0, stream>>>(invx, Bb * (Nn + Mm));
  // E[b][m][n] = exp( dot(tg_m, x_n) * invt[m] * invx[n] )
  gemm_bt1<<<dim3(Mm / 128, Nn / 128, Bb), 256, 0, stream>>>(tgnT, xnT, invt, invx, S, Mm, Nn, Cch);
  // in-place top-k mask on E + rowinv = 1/sum(E)
  row_topk_mask<<<Bb * Mm / 4, 256, 0, stream>>>(S, rowinv);
  // part[b][c][m] = sum_n xb[b][c][n] * Emask[b][m][n]  (wave-async)
  gemm2_wave<<<dim3(Bb, (Cch / 128) * (Mm / 64) * SPLITK, 1), 256, 0, stream>>>(xb, S, part);
  combine_bn<<<Bb * Cch, 256, 0, stream>>>(part, rowinv, out, bnsum);
  bn_finalize<<<1, 256, 0, stream>>>(bnsum, bnw, bnb, scsh);
  final_kernel<<<2048, 256, 0, stream>>>(out, tg, scsh, gamma);
}

// Round 18
// 152.998 us; speedup vs baseline: 1.3157x; 1.0264x over previous
//
#include <hip/hip_runtime.h>
#include <hip/hip_bf16.h>

#define Bb 8
#define Cch 256
#define Nn 2048
#define Mm 2048
#define KKEEP 1638
#define RANK 410   /* Nn - KKEEP, 0-indexed ascending rank of threshold */
#define HGROUPS 4
#define HPITCH 260 /* 4 sub-hists, 4-bank shift/group: cross-group conflict-free */
#define SPLITK2 2

typedef __hip_bfloat16 bf16;
typedef __attribute__((ext_vector_type(8))) short bf16x8;
typedef __attribute__((ext_vector_type(4))) float f32x4;
typedef unsigned int u32;
typedef unsigned short u16;

__device__ __forceinline__ void gload_lds16(const void* g, void* l) {
  __builtin_amdgcn_global_load_lds((const __attribute__((address_space(1))) u32*)g,
                                   (__attribute__((address_space(3))) u32*)l, 16, 0, 0);
}

// ------------- zero accumulators: bnsum(512) + sqx + sqt -------------------
__global__ __launch_bounds__(256) void zero_acc(float* p, int n) {
  int i = blockIdx.x * 256 + threadIdx.x;
  if (i < n) p[i] = 0.f;
}

// ------------- transpose + sumsq: out[b][n][c] = bf16(in[b][c][n]) ---------
// Raw (unnormalized) transpose; accumulates per-(b,n) sum of squares into
// sqacc via one atomicAdd per column per tile. Optionally emits raw bf16
// copy in original [b][c][n] layout (rawb). Norm applied in gemm1 epilogue.
__global__ __launch_bounds__(256) void transpose_sq(const float* __restrict__ in,
                                                    bf16* __restrict__ outp,
                                                    bf16* __restrict__ rawb,
                                                    float* __restrict__ sqacc) {
  __shared__ float tile[32][33];
  __shared__ float sqr[8][33];
  int b = blockIdx.z;
  int n0 = blockIdx.x * 32, c0 = blockIdx.y * 32;
  int tx = threadIdx.x, ty = threadIdx.y;
  const float* src = in + (size_t)b * Cch * Nn;
  float partial = 0.f;
  #pragma unroll
  for (int i = 0; i < 32; i += 8) {
    float v = src[(size_t)(c0 + ty + i) * Nn + n0 + tx];
    tile[ty + i][tx] = v;
    partial += v * v;
    if (rawb) rawb[(size_t)b * Cch * Nn + (size_t)(c0 + ty + i) * Nn + n0 + tx] = __float2bfloat16(v);
  }
  sqr[ty][tx] = partial;
  __syncthreads();
  bf16* dst = outp + (size_t)b * Nn * Cch;
  #pragma unroll
  for (int i = 0; i < 32; i += 8) {
    int n = n0 + ty + i;
    dst[(size_t)n * Cch + c0 + tx] = __float2bfloat16(tile[tx][ty + i]);
  }
  if (ty == 0) {
    float s = 0.f;
    #pragma unroll
    for (int yy = 0; yy < 8; yy++) s += sqr[yy][tx];
    atomicAdd(&sqacc[(b << 11) + n0 + tx], s);
  }
}

// ------------- gemm1: E = bf16(exp(acc * rsq(sqA[m]) * rsq(sqB[n]))) -------
// Raw-input GEMM; cosine normalization applied in the epilogue from the raw
// sum-of-squares buffers (inv computed inline — saves a whole dispatch),
// then exp fused (monotone -> downstream top-k on E == top-k on S).
__global__ __launch_bounds__(256) void gemm_bt1(const bf16* __restrict__ A,
                                                const bf16* __restrict__ Bt,
                                                const float* __restrict__ sqA,
                                                const float* __restrict__ sqB,
                                                bf16* __restrict__ Cout,
                                                int Mrows, int Ncols, int K) {
  __shared__ bf16 aT[128 * 32];
  __shared__ bf16 bT[128 * 32];
  const int b = blockIdx.z;
  const int m0 = blockIdx.x * 128;
  const int n0 = blockIdx.y * 128;
  const bf16* Ab = A + (size_t)b * Mrows * K;
  const bf16* Bbp = Bt + (size_t)b * Ncols * K;
  const int tid = threadIdx.x;
  const int lane = tid & 63;
  const int wave = tid >> 6;
  const int wr = wave >> 1, wc = wave & 1;

  f32x4 acc[4][4];
  #pragma unroll
  for (int i = 0; i < 4; i++)
    #pragma unroll
    for (int j = 0; j < 4; j++) acc[i][j] = (f32x4){0.f, 0.f, 0.f, 0.f};

  const int srow = tid >> 2;
  const int scol = (tid & 3) * 8;
  const bf16* gA0 = Ab + (size_t)(m0 + srow) * K + scol;
  const bf16* gB0 = Bbp + (size_t)(n0 + srow) * K + scol;
  bf16* lA = aT + wave * 512;   // wave-uniform LDS base (lane*16B auto-added)
  bf16* lB = bT + wave * 512;

  const int fm = lane & 15;
  const int kb = (lane >> 4) * 8;

  for (int kt = 0; kt < K; kt += 32) {
    gload_lds16(gA0 + kt, lA);
    gload_lds16(gA0 + (size_t)64 * K + kt, lA + 2048);
    gload_lds16(gB0 + kt, lB);
    gload_lds16(gB0 + (size_t)64 * K + kt, lB + 2048);
    __syncthreads();
    bf16x8 af[4], bf_[4];
    #pragma unroll
    for (int mf = 0; mf < 4; mf++)
      af[mf] = *(const bf16x8*)&aT[(wr * 64 + mf * 16 + fm) * 32 + kb];
    #pragma unroll
    for (int nf = 0; nf < 4; nf++)
      bf_[nf] = *(const bf16x8*)&bT[(wc * 64 + nf * 16 + fm) * 32 + kb];
    #pragma unroll
    for (int mf = 0; mf < 4; mf++)
      #pragma unroll
      for (int nf = 0; nf < 4; nf++)
        acc[mf][nf] = __builtin_amdgcn_mfma_f32_16x16x32_bf16(af[mf], bf_[nf], acc[mf][nf], 0, 0, 0);
    __syncthreads();
  }

  const int orow = (lane >> 4) * 4;
  const int ocol = lane & 15;
  bf16* Cb = Cout + (size_t)b * Mrows * Ncols;
  float ix[4];
  #pragma unroll
  for (int nf = 0; nf < 4; nf++) {
    float s = sqB[(size_t)b * Ncols + n0 + wc * 64 + nf * 16 + ocol];
    ix[nf] = 1.f / fmaxf(sqrtf(s), 1e-12f);
  }
  #pragma unroll
  for (int mf = 0; mf < 4; mf++)
    #pragma unroll
    for (int r = 0; r < 4; r++) {
      int gm = m0 + wr * 64 + mf * 16 + orow + r;
      float sA = sqA[(size_t)b * Mrows + gm];
      float it = 1.f / fmaxf(sqrtf(sA), 1e-12f);
      #pragma unroll
      for (int nf = 0; nf < 4; nf++) {
        int gn = n0 + wc * 64 + nf * 16 + ocol;
        Cb[(size_t)gm * Ncols + gn] = __float2bfloat16(__expf(acc[mf][nf][r] * it * ix[nf]));
      }
    }
}

// ---- wave-level inclusive scan over 64 lanes ------------------------------
__device__ __forceinline__ u32 wave_incl_scan(u32 v, int lane) {
  #pragma unroll
  for (int off = 1; off < 64; off <<= 1) {
    u32 t = __shfl_up(v, off, 64);
    if (lane >= off) v += t;
  }
  return v;
}

// ------------- per-row top-k MASK over E = exp(S), in place ---------------
// ONE WAVE PER ROW. Pure-integer select on the 10-bit biased key
// v = clamp(u - 0x3E00, 0, 0x3FF) (monotone in E). Radix: pass1 v>>2,
// pass2 v&3. Masked write = u16 select. rowinv[row] = 1/sum(E).
__global__ __launch_bounds__(256) void row_topk_mask(bf16* __restrict__ S,
                                                     float* __restrict__ rowinv) {
  const int lane = threadIdx.x & 63;
  const int wv = threadIdx.x >> 6;                 // 0..3
  const int rowIdx = blockIdx.x * 4 + wv;
  bf16* row = S + (size_t)rowIdx * Nn;
  __shared__ u32 hist_s[4][HGROUPS * HPITCH];      // 4 x 4160B
  u32* hist = hist_s[wv];                          // wave-private
  u32* myhist = hist + (lane & (HGROUPS - 1)) * HPITCH;

  // ---- load: slot k holds global elems k*512 + lane*8 .. +7 ----
  uint4 rw[4];
  #pragma unroll
  for (int k = 0; k < 4; k++) rw[k] = ((const uint4*)row)[k * 64 + lane];

  u16 kv[32];
  float se = 0.f;
  #pragma unroll
  for (int k = 0; k < 4; k++) {
    u32 wd[4] = {rw[k].x, rw[k].y, rw[k].z, rw[k].w};
    #pragma unroll
    for (int j = 0; j < 4; j++) {
      u16 a = (u16)(wd[j] & 0xFFFF), b = (u16)(wd[j] >> 16);
      int i0 = k * 8 + 2 * j;
      int va = (int)a - 0x3E00; va = va < 0 ? 0 : (va > 0x3FF ? 0x3FF : va);
      int vb = (int)b - 0x3E00; vb = vb < 0 ? 0 : (vb > 0x3FF ? 0x3FF : vb);
      kv[i0] = (u16)va; kv[i0 + 1] = (u16)vb;
      u32 ba = ((u32)a) << 16, bb = ((u32)b) << 16;
      float fa, fb; __builtin_memcpy(&fa, &ba, 4); __builtin_memcpy(&fb, &bb, 4);
      se += fa + fb;                               // sum of E (denominator)
    }
  }
  #pragma unroll
  for (int off = 32; off > 0; off >>= 1) se += __shfl_xor(se, off, 64);
  if (lane == 0) rowinv[rowIdx] = 1.f / se;

  // ---- radix pass 1: histogram of v>>2 ----
  #pragma unroll
  for (int i = 0; i < 16; i++) hist[i * 64 + lane] = 0;
  if (lane < HGROUPS * HPITCH - 1024) hist[1024 + lane] = 0;
  __threadfence_block();
  #pragma unroll
  for (int i = 0; i < 32; i++) atomicAdd(&myhist[kv[i] >> 2], 1u);
  __threadfence_block();
  u32 h[4], c[4];
  h[0] = h[1] = h[2] = h[3] = 0;
  #pragma unroll
  for (int gg = 0; gg < HGROUPS; gg++) {
    uint4 v = *(const uint4*)&hist[gg * HPITCH + lane * 4];
    h[0] += v.x; h[1] += v.y; h[2] += v.z; h[3] += v.w;
  }
  c[0] = h[0]; c[1] = c[0] + h[1]; c[2] = c[1] + h[2]; c[3] = c[2] + h[3];
  u32 inclTot = wave_incl_scan(c[3], lane);
  u32 pre = inclTot - c[3];                         // exclusive prefix of my 4 bins
  u32 binsel = 0xFFFFFFFFu, belowv = 0;
  #pragma unroll
  for (int i = 0; i < 4; i++) {
    u32 incl = pre + c[i];
    if (incl > (u32)RANK && incl - h[i] <= (u32)RANK) { binsel = lane * 4 + i; belowv = incl - h[i]; }
  }
  unsigned long long mk = __ballot(binsel != 0xFFFFFFFFu);
  int src = __ffsll(mk) - 1;
  u32 b1 = __shfl(binsel, src, 64);
  u32 below = __shfl(belowv, src, 64);

  // ---- radix pass 2: v&3 among keys with v>>2 == b1 ----
  #pragma unroll
  for (int i = 0; i < 16; i++) hist[i * 64 + lane] = 0;
  if (lane < HGROUPS * HPITCH - 1024) hist[1024 + lane] = 0;
  __threadfence_block();
  #pragma unroll
  for (int i = 0; i < 32; i++)
    if ((u32)(kv[i] >> 2) == b1) atomicAdd(&myhist[kv[i] & 3], 1u);
  __threadfence_block();
  h[0] = h[1] = h[2] = h[3] = 0;
  #pragma unroll
  for (int gg = 0; gg < HGROUPS; gg++) {
    uint4 v = *(const uint4*)&hist[gg * HPITCH + lane * 4];
    h[0] += v.x; h[1] += v.y; h[2] += v.z; h[3] += v.w;
  }
  c[0] = h[0]; c[1] = c[0] + h[1]; c[2] = c[1] + h[2]; c[3] = c[2] + h[3];
  inclTot = wave_incl_scan(c[3], lane);
  pre = inclTot - c[3];
  binsel = 0xFFFFFFFFu; u32 totv = 0;
  #pragma unroll
  for (int i = 0; i < 4; i++) {
    u32 incl = below + pre + c[i];
    if (incl > (u32)RANK && incl - h[i] <= (u32)RANK) { binsel = lane * 4 + i; totv = incl; }
  }
  mk = __ballot(binsel != 0xFFFFFFFFu);
  src = __ffsll(mk) - 1;
  u32 lowb = __shfl(binsel, src, 64);               // 0..3 (lane 0's bins)
  u32 totalLE = __shfl(totv, src, 64);              // #keys <= tkey
  u16 tkey = (u16)((b1 << 2) | lowb);
  int keepEq = KKEEP - (Nn - (int)totalLE);         // ties kept, lowest global index first

  // ---- tie ordering: global idx = k*512 + lane*8 + j ----
  int eqk[4];
  #pragma unroll
  for (int k = 0; k < 4; k++) {
    int c2 = 0;
    #pragma unroll
    for (int j = 0; j < 8; j++) c2 += (kv[k * 8 + j] == tkey);
    eqk[k] = c2;
  }
  int eqbase[4]; int running = 0;
  #pragma unroll
  for (int k = 0; k < 4; k++) {
    u32 inclL = wave_incl_scan((u32)eqk[k], lane);
    int waveTot = __shfl((int)inclL, 63, 64);
    eqbase[k] = running + (int)inclL - eqk[k];
    running += waveTot;
  }

  // ---- masked write: keep iff v > tkey, or v == tkey and order < keepEq ---
  #pragma unroll
  for (int k = 0; k < 4; k++) {
    int eqs = eqbase[k];
    u32 wd[4] = {rw[k].x, rw[k].y, rw[k].z, rw[k].w};
    u32 od[4];
    #pragma unroll
    for (int j = 0; j < 4; j++) {
      u16 a = (u16)(wd[j] & 0xFFFF), b = (u16)(wd[j] >> 16);
      int i0 = k * 8 + 2 * j;
      u16 o0 = 0, o1 = 0;
      if (kv[i0] > tkey) o0 = a;
      else if (kv[i0] == tkey) { if (eqs < keepEq) o0 = a; eqs++; }
      if (kv[i0 + 1] > tkey) o1 = b;
      else if (kv[i0 + 1] == tkey) { if (eqs < keepEq) o1 = b; eqs++; }
      od[j] = (u32)o0 | ((u32)o1 << 16);
    }
    uint4 outv = {od[0], od[1], od[2], od[3]};
    ((uint4*)row)[k * 64 + lane] = outv;
  }
}

// ------------- WAVE-ASYNC gemm2: part = xb * Emask^T, split-K partials -----
// r15's proven local optimum: wave-private LDS slices, per-step 6x
// global_load_lds -> s_waitcnt vmcnt(0) (per-wave counter; no barrier) ->
// 8 MFMA. SPLITK=2 (r17's SPLITK=4 regressed: +16MB writes beat +occupancy).
// bf16 partials; grid (8, 128): blockIdx.x = batch pins each to one XCD.
__global__ __launch_bounds__(256) void gemm2_wave(const bf16* __restrict__ A,
                                                  const bf16* __restrict__ Bt,
                                                  bf16* __restrict__ part) {
  constexpr int KS = Nn / SPLITK2;           // 1024 K per slice
  constexpr int NT = KS / 32;                // 32 steps
  constexpr int numTiles = (Cch / 128) * (Mm / 64);   // 64
  __shared__ bf16 aW[4][32 * 32];
  __shared__ bf16 bW[4][64 * 32];
  const int b = blockIdx.x;                  // XCD = dispatch_id % 8 = batch
  int yy = blockIdx.y;
  int tile = yy % numTiles, ks = yy / numTiles;
  int m0 = (tile % (Cch / 128)) * 128;       // m fastest: siblings adjacent
  int n0 = (tile / (Cch / 128)) * 64;
  const bf16* Ab = A + (size_t)b * Cch * Nn;
  const bf16* Bbp = Bt + (size_t)b * Mm * Nn;
  const int lane = threadIdx.x & 63;
  const int w = threadIdx.x >> 6;
  const int srow = lane >> 2;                // 16 rows per gload
  const int scol = (lane & 3) * 8;
  const int kBeg = ks * KS;
  const bf16* gA = Ab + (size_t)(m0 + w * 32 + srow) * Nn + kBeg + scol;
  const bf16* gB = Bbp + (size_t)(n0 + srow) * Nn + kBeg + scol;
  const int fm = lane & 15;
  const int kb = (lane >> 4) * 8;

  f32x4 acc[2][4];
  #pragma unroll
  for (int i = 0; i < 2; i++)
    #pragma unroll
    for (int j = 0; j < 4; j++) acc[i][j] = (f32x4){0.f, 0.f, 0.f, 0.f};

  bf16* lA = &aW[w][0];                      // wave-uniform LDS bases
  bf16* lB = &bW[w][0];

  for (int t = 0; t < NT; ++t) {
    int kt = t * 32;
    gload_lds16(gA + kt, lA);
    gload_lds16(gA + (size_t)16 * Nn + kt, lA + 16 * 32);
    #pragma unroll
    for (int i = 0; i < 4; i++)
      gload_lds16(gB + (size_t)(i * 16) * Nn + kt, lB + i * 16 * 32);
    asm volatile("s_waitcnt vmcnt(0)" ::: "memory");
    bf16x8 af[2], bf_[4];
    #pragma unroll
    for (int mf = 0; mf < 2; mf++)
      af[mf] = *(const bf16x8*)&aW[w][(mf * 16 + fm) * 32 + kb];
    #pragma unroll
    for (int nf = 0; nf < 4; nf++)
      bf_[nf] = *(const bf16x8*)&bW[w][(nf * 16 + fm) * 32 + kb];
    #pragma unroll
    for (int mf = 0; mf < 2; mf++)
      #pragma unroll
      for (int nf = 0; nf < 4; nf++)
        acc[mf][nf] = __builtin_amdgcn_mfma_f32_16x16x32_bf16(af[mf], bf_[nf], acc[mf][nf], 0, 0, 0);
  }

  const int orow = (lane >> 4) * 4;
  const int ocol = lane & 15;
  bf16* Pb = part + ((size_t)ks * Bb + b) * Cch * Mm;
  #pragma unroll
  for (int mf = 0; mf < 2; mf++)
    #pragma unroll
    for (int nf = 0; nf < 4; nf++)
      #pragma unroll
      for (int r = 0; r < 4; r++) {
        int gm = m0 + w * 32 + mf * 16 + orow + r;
        int gn = n0 + nf * 16 + ocol;
        Pb[(size_t)gm * Mm + gn] = __float2bfloat16(acc[mf][nf][r]);
      }
}

// ------------- combine split-K bf16 partials: *inv[m], leaky, BN, y(bf16) --
__global__ __launch_bounds__(256) void combine_bn(const bf16* __restrict__ part,
                                                  const float* __restrict__ rowinv,
                                                  bf16* __restrict__ ybf,
                                                  float* __restrict__ bnsum) {
  int bc = blockIdx.x;                       // b*Cch + c
  int b = bc >> 8;
  int tid = threadIdx.x;
  size_t sl = (size_t)Bb * Cch * Mm;
  uint4 a0 = ((const uint4*)(part + (size_t)bc * Mm))[tid];        // 8 bf16
  uint4 a1 = ((const uint4*)(part + sl + (size_t)bc * Mm))[tid];
  const float4* iv = (const float4*)(rowinv + (size_t)b * Mm);
  float4 w0 = iv[tid * 2], w1 = iv[tid * 2 + 1];
  float v[8];
  #pragma unroll
  for (int j = 0; j < 4; j++) {
    u32 x0 = ((const u32*)&a0)[j], x1 = ((const u32*)&a1)[j];
    u32 lo0 = x0 << 16, hi0 = x0 & 0xFFFF0000u;
    u32 lo1 = x1 << 16, hi1 = x1 & 0xFFFF0000u;
    float f0, f1, g0, g1;
    __builtin_memcpy(&f0, &lo0, 4); __builtin_memcpy(&f1, &hi0, 4);
    __builtin_memcpy(&g0, &lo1, 4); __builtin_memcpy(&g1, &hi1, 4);
    v[2 * j] = f0 + g0; v[2 * j + 1] = f1 + g1;
  }
  v[0] *= w0.x; v[1] *= w0.y; v[2] *= w0.z; v[3] *= w0.w;
  v[4] *= w1.x; v[5] *= w1.y; v[6] *= w1.z; v[7] *= w1.w;
  float s = 0.f, ss = 0.f;
  union { u16 h[8]; uint4 u; } pk;
  #pragma unroll
  for (int j = 0; j < 8; j++) {
    float y = v[j];
    y = y >= 0.f ? y : 0.01f * y;
    s += y; ss += y * y;
    bf16 t = __float2bfloat16(y);
    __builtin_memcpy(&pk.h[j], &t, 2);
  }
  ((uint4*)(ybf + (size_t)bc * Mm))[tid] = pk.u;
  __shared__ float r1[256], r2[256];
  r1[tid] = s; r2[tid] = ss; __syncthreads();
  for (int k = 128; k > 0; k >>= 1) {
    if (tid < k) { r1[tid] += r1[tid + k]; r2[tid] += r2[tid + k]; }
    __syncthreads();
  }
  if (tid == 0) {
    int c = bc & (Cch - 1);
    atomicAdd(&bnsum[c], r1[0]);
    atomicAdd(&bnsum[Cch + c], r2[0]);
  }
}

// ------------- BN finalize: scale/shift per channel ------------------------
__global__ __launch_bounds__(256) void bn_finalize(const float* __restrict__ bnsum,
                                                   const float* __restrict__ bnw,
                                                   const float* __restrict__ bnb,
                                                   float* __restrict__ scsh) {
  int c = threadIdx.x;
  float cnt = (float)(Bb * Mm);
  float mean = bnsum[c] / cnt;
  float var = bnsum[Cch + c] / cnt - mean * mean;
  float scale = bnw[c] / sqrtf(var + 1e-5f);
  scsh[c * 2] = scale;
  scsh[c * 2 + 1] = bnb[c] - mean * scale;
}

// ------------- final: out = (y*scale+shift)*gamma + tg (y read as bf16) ----
__global__ __launch_bounds__(256) void final_kernel(const bf16* __restrict__ ybf,
                                                    float* __restrict__ outp,
                                                    const float* __restrict__ tg,
                                                    const float* __restrict__ scsh,
                                                    const float* __restrict__ gamma) {
  size_t n8 = (size_t)Bb * Cch * Mm / 8;
  float g = gamma[0];
  size_t stride = (size_t)gridDim.x * 256;
  for (size_t i = (size_t)blockIdx.x * 256 + threadIdx.x; i < n8; i += stride) {
    int c = (int)((i * 8 / Mm) % Cch);
    uint4 yv = ((const uint4*)ybf)[i];
    float sc = scsh[c * 2] * g, sh = scsh[c * 2 + 1] * g;
    const float4* tp = (const float4*)tg + i * 2;
    float4* op = (float4*)outp + i * 2;
    #pragma unroll
    for (int half = 0; half < 2; half++) {
      float4 t = tp[half];
      u32 wa = ((const u32*)&yv)[half * 2], wb = ((const u32*)&yv)[half * 2 + 1];
      u32 b0 = wa << 16, b1 = wa & 0xFFFF0000u, b2 = wb << 16, b3 = wb & 0xFFFF0000u;
      float y0, y1, y2, y3;
      __builtin_memcpy(&y0, &b0, 4); __builtin_memcpy(&y1, &b1, 4);
      __builtin_memcpy(&y2, &b2, 4); __builtin_memcpy(&y3, &b3, 4);
      float4 o;
      o.x = y0 * sc + sh + t.x;
      o.y = y1 * sc + sh + t.y;
      o.z = y2 * sc + sh + t.z;
      o.w = y3 * sc + sh + t.w;
      op[half] = o;
    }
  }
}

extern "C" void kernel_launch(void* const* d_in, const int* in_sizes, int n_in,
                              void* d_out, int out_size, void* d_ws, size_t ws_size,
                              hipStream_t stream) {
  (void)in_sizes; (void)n_in; (void)out_size; (void)ws_size;
  const float* x   = (const float*)d_in[0];
  const float* tg  = (const float*)d_in[1];
  const float* gamma = (const float*)d_in[2];
  const float* bnw = (const float*)d_in[3];
  const float* bnb = (const float*)d_in[4];
  float* out = (float*)d_out;

  char* ws = (char*)d_ws;
  bf16* xnT  = (bf16*)ws; ws += (size_t)Bb * Nn * Cch * 2;
  bf16* tgnT = (bf16*)ws; ws += (size_t)Bb * Mm * Cch * 2;
  bf16* xb   = (bf16*)ws; ws += (size_t)Bb * Cch * Nn * 2;
  bf16* S    = (bf16*)ws; ws += (size_t)Bb * Mm * Nn * 2;   // holds E = exp(S)
  bf16* part = (bf16*)ws; ws += (size_t)SPLITK2 * Bb * Cch * Mm * 2;
  bf16* ybf  = (bf16*)ws; ws += (size_t)Bb * Cch * Mm * 2;
  float* rowinv = (float*)ws; ws += (size_t)Bb * Mm * 4;
  // contiguous accumulator block (zeroed each launch):
  float* bnsum = (float*)ws; ws += (size_t)2 * Cch * 4;
  float* sqx   = (float*)ws; ws += (size_t)Bb * Nn * 4;     // raw sum-of-squares
  float* sqt   = (float*)ws; ws += (size_t)Bb * Mm * 4;
  float* scsh  = (float*)ws; ws += (size_t)Cch * 2 * 4;
  const int accN = 2 * Cch + Bb * Nn + Bb * Mm;             // 33280 floats

  zero_acc<<<(accN + 255) / 256, 256, 0, stream>>>(bnsum, accN);
  transpose_sq<<<dim3(Nn / 32, Cch / 32, Bb), dim3(32, 8), 0, stream>>>(x, xnT, xb, sqx);
  transpose_sq<<<dim3(Mm / 32, Cch / 32, Bb), dim3(32, 8), 0, stream>>>(tg, tgnT, nullptr, sqt);
  // E[b][m][n] = exp( dot(tg_m, x_n) * rsq(sqt[m]) * rsq(sqx[n]) )
  gemm_bt1<<<dim3(Mm / 128, Nn / 128, Bb), 256, 0, stream>>>(tgnT, xnT, sqt, sqx, S, Mm, Nn, Cch);
  // in-place top-k mask on E + rowinv = 1/sum(E)
  row_topk_mask<<<Bb * Mm / 4, 256, 0, stream>>>(S, rowinv);
  // part[b][c][m] = sum_n xb[b][c][n] * Emask[b][m][n]  (wave-async)
  gemm2_wave<<<dim3(Bb, (Cch / 128) * (Mm / 64) * SPLITK2, 1), 256, 0, stream>>>(xb, S, part);
  combine_bn<<<Bb * Cch, 256, 0, stream>>>(part, rowinv, ybf, bnsum);
  bn_finalize<<<1, 256, 0, stream>>>(bnsum, bnw, bnb, scsh);
  final_kernel<<<2048, 256, 0, stream>>>(ybf, out, tg, scsh, gamma);
}

// Round 19
// 149.738 us; speedup vs baseline: 1.3443x; 1.0218x over previous
//
#include <hip/hip_runtime.h>
#include <hip/hip_bf16.h>

#define Bb 8
#define Cch 256
#define Nn 2048
#define Mm 2048
#define KKEEP 1638
#define RANK 410   /* Nn - KKEEP, 0-indexed ascending rank of threshold */
#define HGROUPS 4
#define HPITCH 260 /* 4 sub-hists, 4-bank shift/group: cross-group conflict-free */
#define SPLITK2 2

typedef __hip_bfloat16 bf16;
typedef __attribute__((ext_vector_type(8))) short bf16x8;
typedef __attribute__((ext_vector_type(4))) float f32x4;
typedef unsigned int u32;
typedef unsigned short u16;

__device__ __forceinline__ void gload_lds16(const void* g, void* l) {
  __builtin_amdgcn_global_load_lds((const __attribute__((address_space(1))) u32*)g,
                                   (__attribute__((address_space(3))) u32*)l, 16, 0, 0);
}

// ------------- zero accumulators: bnsum(512) + sqx + sqt -------------------
__global__ __launch_bounds__(256) void zero_acc(float* p, int n) {
  int i = blockIdx.x * 256 + threadIdx.x;
  if (i < n) p[i] = 0.f;
}

// ------------- transpose + sumsq: out[b][n][c] = bf16(in[b][c][n]) ---------
// Raw (unnormalized) transpose; accumulates per-(b,n) sum of squares into
// sqacc via one atomicAdd per column per tile. Optionally emits raw bf16
// copy in original [b][c][n] layout (rawb). Norm applied in gemm1 epilogue.
__global__ __launch_bounds__(256) void transpose_sq(const float* __restrict__ in,
                                                    bf16* __restrict__ outp,
                                                    bf16* __restrict__ rawb,
                                                    float* __restrict__ sqacc) {
  __shared__ float tile[32][33];
  __shared__ float sqr[8][33];
  int b = blockIdx.z;
  int n0 = blockIdx.x * 32, c0 = blockIdx.y * 32;
  int tx = threadIdx.x, ty = threadIdx.y;
  const float* src = in + (size_t)b * Cch * Nn;
  float partial = 0.f;
  #pragma unroll
  for (int i = 0; i < 32; i += 8) {
    float v = src[(size_t)(c0 + ty + i) * Nn + n0 + tx];
    tile[ty + i][tx] = v;
    partial += v * v;
    if (rawb) rawb[(size_t)b * Cch * Nn + (size_t)(c0 + ty + i) * Nn + n0 + tx] = __float2bfloat16(v);
  }
  sqr[ty][tx] = partial;
  __syncthreads();
  bf16* dst = outp + (size_t)b * Nn * Cch;
  #pragma unroll
  for (int i = 0; i < 32; i += 8) {
    int n = n0 + ty + i;
    dst[(size_t)n * Cch + c0 + tx] = __float2bfloat16(tile[tx][ty + i]);
  }
  if (ty == 0) {
    float s = 0.f;
    #pragma unroll
    for (int yy = 0; yy < 8; yy++) s += sqr[yy][tx];
    atomicAdd(&sqacc[(b << 11) + n0 + tx], s);
  }
}

// ------------- gemm1: E = bf16(exp(acc * rsq(sqA[m]) * rsq(sqB[n]))) -------
// 2-phase double-buffered K-loop (the r10 transform that cut gemm2 85->62):
// issue next K-tile's global_load_lds BEFORE computing current, one barrier
// per iter so HBM latency elapses under MFMA+ds_read. XCD-pinned grid
// (8, 256): blockIdx.x = batch, m fastest (L2 locality for tgnT/xnT).
// Cosine norm from raw sum-of-squares + exp fused in epilogue.
__global__ __launch_bounds__(256) void gemm_bt1(const bf16* __restrict__ A,
                                                const bf16* __restrict__ Bt,
                                                const float* __restrict__ sqA,
                                                const float* __restrict__ sqB,
                                                bf16* __restrict__ Cout,
                                                int Mrows, int Ncols, int K) {
  __shared__ bf16 aT[2][128 * 32];
  __shared__ bf16 bT[2][128 * 32];
  const int b = blockIdx.x;                  // XCD = dispatch_id % 8 = batch
  const int yy = blockIdx.y;
  const int m0 = (yy & 15) * 128;            // m fastest: siblings adjacent
  const int n0 = (yy >> 4) * 128;
  const bf16* Ab = A + (size_t)b * Mrows * K;
  const bf16* Bbp = Bt + (size_t)b * Ncols * K;
  const int tid = threadIdx.x;
  const int lane = tid & 63;
  const int wave = tid >> 6;
  const int wr = wave >> 1, wc = wave & 1;

  f32x4 acc[4][4];
  #pragma unroll
  for (int i = 0; i < 4; i++)
    #pragma unroll
    for (int j = 0; j < 4; j++) acc[i][j] = (f32x4){0.f, 0.f, 0.f, 0.f};

  const int srow = tid >> 2;
  const int scol = (tid & 3) * 8;
  const bf16* gA0 = Ab + (size_t)(m0 + srow) * K + scol;
  const bf16* gB0 = Bbp + (size_t)(n0 + srow) * K + scol;

  const int fm = lane & 15;
  const int kb = (lane >> 4) * 8;
  const int NT = K / 32;                     // 8

  auto stage = [&](int buf, int kt) {
    bf16* lA = aT[buf] + wave * 512;         // wave-uniform LDS base
    bf16* lB = bT[buf] + wave * 512;
    gload_lds16(gA0 + kt, lA);
    gload_lds16(gA0 + (size_t)64 * K + kt, lA + 2048);
    gload_lds16(gB0 + kt, lB);
    gload_lds16(gB0 + (size_t)64 * K + kt, lB + 2048);
  };

  stage(0, 0);
  __syncthreads();
  int cur = 0;
  for (int t = 0; t < NT; ++t) {
    if (t + 1 < NT) stage(cur ^ 1, (t + 1) * 32);  // overlaps compute below
    const bf16* cA = aT[cur];
    const bf16* cB = bT[cur];
    bf16x8 af[4], bf_[4];
    #pragma unroll
    for (int mf = 0; mf < 4; mf++)
      af[mf] = *(const bf16x8*)&cA[(wr * 64 + mf * 16 + fm) * 32 + kb];
    #pragma unroll
    for (int nf = 0; nf < 4; nf++)
      bf_[nf] = *(const bf16x8*)&cB[(wc * 64 + nf * 16 + fm) * 32 + kb];
    #pragma unroll
    for (int mf = 0; mf < 4; mf++)
      #pragma unroll
      for (int nf = 0; nf < 4; nf++)
        acc[mf][nf] = __builtin_amdgcn_mfma_f32_16x16x32_bf16(af[mf], bf_[nf], acc[mf][nf], 0, 0, 0);
    __syncthreads();
    cur ^= 1;
  }

  const int orow = (lane >> 4) * 4;
  const int ocol = lane & 15;
  bf16* Cb = Cout + (size_t)b * Mrows * Ncols;
  float ix[4];
  #pragma unroll
  for (int nf = 0; nf < 4; nf++) {
    float s = sqB[(size_t)b * Ncols + n0 + wc * 64 + nf * 16 + ocol];
    ix[nf] = 1.f / fmaxf(sqrtf(s), 1e-12f);
  }
  #pragma unroll
  for (int mf = 0; mf < 4; mf++)
    #pragma unroll
    for (int r = 0; r < 4; r++) {
      int gm = m0 + wr * 64 + mf * 16 + orow + r;
      float sA = sqA[(size_t)b * Mrows + gm];
      float it = 1.f / fmaxf(sqrtf(sA), 1e-12f);
      #pragma unroll
      for (int nf = 0; nf < 4; nf++) {
        int gn = n0 + wc * 64 + nf * 16 + ocol;
        Cb[(size_t)gm * Ncols + gn] = __float2bfloat16(__expf(acc[mf][nf][r] * it * ix[nf]));
      }
    }
}

// ---- wave-level inclusive scan over 64 lanes ------------------------------
__device__ __forceinline__ u32 wave_incl_scan(u32 v, int lane) {
  #pragma unroll
  for (int off = 1; off < 64; off <<= 1) {
    u32 t = __shfl_up(v, off, 64);
    if (lane >= off) v += t;
  }
  return v;
}

// ------------- per-row top-k MASK over E = exp(S), in place ---------------
// ONE WAVE PER ROW. Pure-integer select on the 10-bit biased key
// v = clamp(u - 0x3E00, 0, 0x3FF) (monotone in E). Radix: pass1 v>>2,
// pass2 v&3. Masked write = u16 select. rowinv[row] = 1/sum(E).
__global__ __launch_bounds__(256) void row_topk_mask(bf16* __restrict__ S,
                                                     float* __restrict__ rowinv) {
  const int lane = threadIdx.x & 63;
  const int wv = threadIdx.x >> 6;                 // 0..3
  const int rowIdx = blockIdx.x * 4 + wv;
  bf16* row = S + (size_t)rowIdx * Nn;
  __shared__ u32 hist_s[4][HGROUPS * HPITCH];      // 4 x 4160B
  u32* hist = hist_s[wv];                          // wave-private
  u32* myhist = hist + (lane & (HGROUPS - 1)) * HPITCH;

  // ---- load: slot k holds global elems k*512 + lane*8 .. +7 ----
  uint4 rw[4];
  #pragma unroll
  for (int k = 0; k < 4; k++) rw[k] = ((const uint4*)row)[k * 64 + lane];

  u16 kv[32];
  float se = 0.f;
  #pragma unroll
  for (int k = 0; k < 4; k++) {
    u32 wd[4] = {rw[k].x, rw[k].y, rw[k].z, rw[k].w};
    #pragma unroll
    for (int j = 0; j < 4; j++) {
      u16 a = (u16)(wd[j] & 0xFFFF), b = (u16)(wd[j] >> 16);
      int i0 = k * 8 + 2 * j;
      int va = (int)a - 0x3E00; va = va < 0 ? 0 : (va > 0x3FF ? 0x3FF : va);
      int vb = (int)b - 0x3E00; vb = vb < 0 ? 0 : (vb > 0x3FF ? 0x3FF : vb);
      kv[i0] = (u16)va; kv[i0 + 1] = (u16)vb;
      u32 ba = ((u32)a) << 16, bb = ((u32)b) << 16;
      float fa, fb; __builtin_memcpy(&fa, &ba, 4); __builtin_memcpy(&fb, &bb, 4);
      se += fa + fb;                               // sum of E (denominator)
    }
  }
  #pragma unroll
  for (int off = 32; off > 0; off >>= 1) se += __shfl_xor(se, off, 64);
  if (lane == 0) rowinv[rowIdx] = 1.f / se;

  // ---- radix pass 1: histogram of v>>2 ----
  #pragma unroll
  for (int i = 0; i < 16; i++) hist[i * 64 + lane] = 0;
  if (lane < HGROUPS * HPITCH - 1024) hist[1024 + lane] = 0;
  __threadfence_block();
  #pragma unroll
  for (int i = 0; i < 32; i++) atomicAdd(&myhist[kv[i] >> 2], 1u);
  __threadfence_block();
  u32 h[4], c[4];
  h[0] = h[1] = h[2] = h[3] = 0;
  #pragma unroll
  for (int gg = 0; gg < HGROUPS; gg++) {
    uint4 v = *(const uint4*)&hist[gg * HPITCH + lane * 4];
    h[0] += v.x; h[1] += v.y; h[2] += v.z; h[3] += v.w;
  }
  c[0] = h[0]; c[1] = c[0] + h[1]; c[2] = c[1] + h[2]; c[3] = c[2] + h[3];
  u32 inclTot = wave_incl_scan(c[3], lane);
  u32 pre = inclTot - c[3];                         // exclusive prefix of my 4 bins
  u32 binsel = 0xFFFFFFFFu, belowv = 0;
  #pragma unroll
  for (int i = 0; i < 4; i++) {
    u32 incl = pre + c[i];
    if (incl > (u32)RANK && incl - h[i] <= (u32)RANK) { binsel = lane * 4 + i; belowv = incl - h[i]; }
  }
  unsigned long long mk = __ballot(binsel != 0xFFFFFFFFu);
  int src = __ffsll(mk) - 1;
  u32 b1 = __shfl(binsel, src, 64);
  u32 below = __shfl(belowv, src, 64);

  // ---- radix pass 2: v&3 among keys with v>>2 == b1 ----
  #pragma unroll
  for (int i = 0; i < 16; i++) hist[i * 64 + lane] = 0;
  if (lane < HGROUPS * HPITCH - 1024) hist[1024 + lane] = 0;
  __threadfence_block();
  #pragma unroll
  for (int i = 0; i < 32; i++)
    if ((u32)(kv[i] >> 2) == b1) atomicAdd(&myhist[kv[i] & 3], 1u);
  __threadfence_block();
  h[0] = h[1] = h[2] = h[3] = 0;
  #pragma unroll
  for (int gg = 0; gg < HGROUPS; gg++) {
    uint4 v = *(const uint4*)&hist[gg * HPITCH + lane * 4];
    h[0] += v.x; h[1] += v.y; h[2] += v.z; h[3] += v.w;
  }
  c[0] = h[0]; c[1] = c[0] + h[1]; c[2] = c[1] + h[2]; c[3] = c[2] + h[3];
  inclTot = wave_incl_scan(c[3], lane);
  pre = inclTot - c[3];
  binsel = 0xFFFFFFFFu; u32 totv = 0;
  #pragma unroll
  for (int i = 0; i < 4; i++) {
    u32 incl = below + pre + c[i];
    if (incl > (u32)RANK && incl - h[i] <= (u32)RANK) { binsel = lane * 4 + i; totv = incl; }
  }
  mk = __ballot(binsel != 0xFFFFFFFFu);
  src = __ffsll(mk) - 1;
  u32 lowb = __shfl(binsel, src, 64);               // 0..3 (lane 0's bins)
  u32 totalLE = __shfl(totv, src, 64);              // #keys <= tkey
  u16 tkey = (u16)((b1 << 2) | lowb);
  int keepEq = KKEEP - (Nn - (int)totalLE);         // ties kept, lowest global index first

  // ---- tie ordering: global idx = k*512 + lane*8 + j ----
  int eqk[4];
  #pragma unroll
  for (int k = 0; k < 4; k++) {
    int c2 = 0;
    #pragma unroll
    for (int j = 0; j < 8; j++) c2 += (kv[k * 8 + j] == tkey);
    eqk[k] = c2;
  }
  int eqbase[4]; int running = 0;
  #pragma unroll
  for (int k = 0; k < 4; k++) {
    u32 inclL = wave_incl_scan((u32)eqk[k], lane);
    int waveTot = __shfl((int)inclL, 63, 64);
    eqbase[k] = running + (int)inclL - eqk[k];
    running += waveTot;
  }

  // ---- masked write: keep iff v > tkey, or v == tkey and order < keepEq ---
  #pragma unroll
  for (int k = 0; k < 4; k++) {
    int eqs = eqbase[k];
    u32 wd[4] = {rw[k].x, rw[k].y, rw[k].z, rw[k].w};
    u32 od[4];
    #pragma unroll
    for (int j = 0; j < 4; j++) {
      u16 a = (u16)(wd[j] & 0xFFFF), b = (u16)(wd[j] >> 16);
      int i0 = k * 8 + 2 * j;
      u16 o0 = 0, o1 = 0;
      if (kv[i0] > tkey) o0 = a;
      else if (kv[i0] == tkey) { if (eqs < keepEq) o0 = a; eqs++; }
      if (kv[i0 + 1] > tkey) o1 = b;
      else if (kv[i0 + 1] == tkey) { if (eqs < keepEq) o1 = b; eqs++; }
      od[j] = (u32)o0 | ((u32)o1 << 16);
    }
    uint4 outv = {od[0], od[1], od[2], od[3]};
    ((uint4*)row)[k * 64 + lane] = outv;
  }
}

// ------------- WAVE-ASYNC gemm2: part = xb * Emask^T, split-K partials -----
// r15's proven local optimum: wave-private LDS slices, per-step 6x
// global_load_lds -> s_waitcnt vmcnt(0) (per-wave counter; no barrier) ->
// 8 MFMA. SPLITK=2. bf16 partials; grid (8, 128): blockIdx.x = batch = XCD.
__global__ __launch_bounds__(256) void gemm2_wave(const bf16* __restrict__ A,
                                                  const bf16* __restrict__ Bt,
                                                  bf16* __restrict__ part) {
  constexpr int KS = Nn / SPLITK2;           // 1024 K per slice
  constexpr int NT = KS / 32;                // 32 steps
  constexpr int numTiles = (Cch / 128) * (Mm / 64);   // 64
  __shared__ bf16 aW[4][32 * 32];
  __shared__ bf16 bW[4][64 * 32];
  const int b = blockIdx.x;                  // XCD = dispatch_id % 8 = batch
  int yy = blockIdx.y;
  int tile = yy % numTiles, ks = yy / numTiles;
  int m0 = (tile % (Cch / 128)) * 128;       // m fastest: siblings adjacent
  int n0 = (tile / (Cch / 128)) * 64;
  const bf16* Ab = A + (size_t)b * Cch * Nn;
  const bf16* Bbp = Bt + (size_t)b * Mm * Nn;
  const int lane = threadIdx.x & 63;
  const int w = threadIdx.x >> 6;
  const int srow = lane >> 2;                // 16 rows per gload
  const int scol = (lane & 3) * 8;
  const int kBeg = ks * KS;
  const bf16* gA = Ab + (size_t)(m0 + w * 32 + srow) * Nn + kBeg + scol;
  const bf16* gB = Bbp + (size_t)(n0 + srow) * Nn + kBeg + scol;
  const int fm = lane & 15;
  const int kb = (lane >> 4) * 8;

  f32x4 acc[2][4];
  #pragma unroll
  for (int i = 0; i < 2; i++)
    #pragma unroll
    for (int j = 0; j < 4; j++) acc[i][j] = (f32x4){0.f, 0.f, 0.f, 0.f};

  bf16* lA = &aW[w][0];                      // wave-uniform LDS bases
  bf16* lB = &bW[w][0];

  for (int t = 0; t < NT; ++t) {
    int kt = t * 32;
    gload_lds16(gA + kt, lA);
    gload_lds16(gA + (size_t)16 * Nn + kt, lA + 16 * 32);
    #pragma unroll
    for (int i = 0; i < 4; i++)
      gload_lds16(gB + (size_t)(i * 16) * Nn + kt, lB + i * 16 * 32);
    asm volatile("s_waitcnt vmcnt(0)" ::: "memory");
    bf16x8 af[2], bf_[4];
    #pragma unroll
    for (int mf = 0; mf < 2; mf++)
      af[mf] = *(const bf16x8*)&aW[w][(mf * 16 + fm) * 32 + kb];
    #pragma unroll
    for (int nf = 0; nf < 4; nf++)
      bf_[nf] = *(const bf16x8*)&bW[w][(nf * 16 + fm) * 32 + kb];
    #pragma unroll
    for (int mf = 0; mf < 2; mf++)
      #pragma unroll
      for (int nf = 0; nf < 4; nf++)
        acc[mf][nf] = __builtin_amdgcn_mfma_f32_16x16x32_bf16(af[mf], bf_[nf], acc[mf][nf], 0, 0, 0);
  }

  const int orow = (lane >> 4) * 4;
  const int ocol = lane & 15;
  bf16* Pb = part + ((size_t)ks * Bb + b) * Cch * Mm;
  #pragma unroll
  for (int mf = 0; mf < 2; mf++)
    #pragma unroll
    for (int nf = 0; nf < 4; nf++)
      #pragma unroll
      for (int r = 0; r < 4; r++) {
        int gm = m0 + w * 32 + mf * 16 + orow + r;
        int gn = n0 + nf * 16 + ocol;
        Pb[(size_t)gm * Mm + gn] = __float2bfloat16(acc[mf][nf][r]);
      }
}

// ------------- combine split-K bf16 partials: *inv[m], leaky, BN, y(bf16) --
__global__ __launch_bounds__(256) void combine_bn(const bf16* __restrict__ part,
                                                  const float* __restrict__ rowinv,
                                                  bf16* __restrict__ ybf,
                                                  float* __restrict__ bnsum) {
  int bc = blockIdx.x;                       // b*Cch + c
  int b = bc >> 8;
  int tid = threadIdx.x;
  size_t sl = (size_t)Bb * Cch * Mm;
  uint4 a0 = ((const uint4*)(part + (size_t)bc * Mm))[tid];        // 8 bf16
  uint4 a1 = ((const uint4*)(part + sl + (size_t)bc * Mm))[tid];
  const float4* iv = (const float4*)(rowinv + (size_t)b * Mm);
  float4 w0 = iv[tid * 2], w1 = iv[tid * 2 + 1];
  float v[8];
  #pragma unroll
  for (int j = 0; j < 4; j++) {
    u32 x0 = ((const u32*)&a0)[j], x1 = ((const u32*)&a1)[j];
    u32 lo0 = x0 << 16, hi0 = x0 & 0xFFFF0000u;
    u32 lo1 = x1 << 16, hi1 = x1 & 0xFFFF0000u;
    float f0, f1, g0, g1;
    __builtin_memcpy(&f0, &lo0, 4); __builtin_memcpy(&f1, &hi0, 4);
    __builtin_memcpy(&g0, &lo1, 4); __builtin_memcpy(&g1, &hi1, 4);
    v[2 * j] = f0 + g0; v[2 * j + 1] = f1 + g1;
  }
  v[0] *= w0.x; v[1] *= w0.y; v[2] *= w0.z; v[3] *= w0.w;
  v[4] *= w1.x; v[5] *= w1.y; v[6] *= w1.z; v[7] *= w1.w;
  float s = 0.f, ss = 0.f;
  union { u16 h[8]; uint4 u; } pk;
  #pragma unroll
  for (int j = 0; j < 8; j++) {
    float y = v[j];
    y = y >= 0.f ? y : 0.01f * y;
    s += y; ss += y * y;
    bf16 t = __float2bfloat16(y);
    __builtin_memcpy(&pk.h[j], &t, 2);
  }
  ((uint4*)(ybf + (size_t)bc * Mm))[tid] = pk.u;
  __shared__ float r1[256], r2[256];
  r1[tid] = s; r2[tid] = ss; __syncthreads();
  for (int k = 128; k > 0; k >>= 1) {
    if (tid < k) { r1[tid] += r1[tid + k]; r2[tid] += r2[tid + k]; }
    __syncthreads();
  }
  if (tid == 0) {
    int c = bc & (Cch - 1);
    atomicAdd(&bnsum[c], r1[0]);
    atomicAdd(&bnsum[Cch + c], r2[0]);
  }
}

// ------------- BN finalize: scale/shift per channel ------------------------
__global__ __launch_bounds__(256) void bn_finalize(const float* __restrict__ bnsum,
                                                   const float* __restrict__ bnw,
                                                   const float* __restrict__ bnb,
                                                   float* __restrict__ scsh) {
  int c = threadIdx.x;
  float cnt = (float)(Bb * Mm);
  float mean = bnsum[c] / cnt;
  float var = bnsum[Cch + c] / cnt - mean * mean;
  float scale = bnw[c] / sqrtf(var + 1e-5f);
  scsh[c * 2] = scale;
  scsh[c * 2 + 1] = bnb[c] - mean * scale;
}

// ------------- final: out = (y*scale+shift)*gamma + tg (y read as bf16) ----
__global__ __launch_bounds__(256) void final_kernel(const bf16* __restrict__ ybf,
                                                    float* __restrict__ outp,
                                                    const float* __restrict__ tg,
                                                    const float* __restrict__ scsh,
                                                    const float* __restrict__ gamma) {
  size_t n8 = (size_t)Bb * Cch * Mm / 8;
  float g = gamma[0];
  size_t stride = (size_t)gridDim.x * 256;
  for (size_t i = (size_t)blockIdx.x * 256 + threadIdx.x; i < n8; i += stride) {
    int c = (int)((i * 8 / Mm) % Cch);
    uint4 yv = ((const uint4*)ybf)[i];
    float sc = scsh[c * 2] * g, sh = scsh[c * 2 + 1] * g;
    const float4* tp = (const float4*)tg + i * 2;
    float4* op = (float4*)outp + i * 2;
    #pragma unroll
    for (int half = 0; half < 2; half++) {
      float4 t = tp[half];
      u32 wa = ((const u32*)&yv)[half * 2], wb = ((const u32*)&yv)[half * 2 + 1];
      u32 b0 = wa << 16, b1 = wa & 0xFFFF0000u, b2 = wb << 16, b3 = wb & 0xFFFF0000u;
      float y0, y1, y2, y3;
      __builtin_memcpy(&y0, &b0, 4); __builtin_memcpy(&y1, &b1, 4);
      __builtin_memcpy(&y2, &b2, 4); __builtin_memcpy(&y3, &b3, 4);
      float4 o;
      o.x = y0 * sc + sh + t.x;
      o.y = y1 * sc + sh + t.y;
      o.z = y2 * sc + sh + t.z;
      o.w = y3 * sc + sh + t.w;
      op[half] = o;
    }
  }
}

extern "C" void kernel_launch(void* const* d_in, const int* in_sizes, int n_in,
                              void* d_out, int out_size, void* d_ws, size_t ws_size,
                              hipStream_t stream) {
  (void)in_sizes; (void)n_in; (void)out_size; (void)ws_size;
  const float* x   = (const float*)d_in[0];
  const float* tg  = (const float*)d_in[1];
  const float* gamma = (const float*)d_in[2];
  const float* bnw = (const float*)d_in[3];
  const float* bnb = (const float*)d_in[4];
  float* out = (float*)d_out;

  char* ws = (char*)d_ws;
  bf16* xnT  = (bf16*)ws; ws += (size_t)Bb * Nn * Cch * 2;
  bf16* tgnT = (bf16*)ws; ws += (size_t)Bb * Mm * Cch * 2;
  bf16* xb   = (bf16*)ws; ws += (size_t)Bb * Cch * Nn * 2;
  bf16* S    = (bf16*)ws; ws += (size_t)Bb * Mm * Nn * 2;   // holds E = exp(S)
  bf16* part = (bf16*)ws; ws += (size_t)SPLITK2 * Bb * Cch * Mm * 2;
  bf16* ybf  = (bf16*)ws; ws += (size_t)Bb * Cch * Mm * 2;
  float* rowinv = (float*)ws; ws += (size_t)Bb * Mm * 4;
  // contiguous accumulator block (zeroed each launch):
  float* bnsum = (float*)ws; ws += (size_t)2 * Cch * 4;
  float* sqx   = (float*)ws; ws += (size_t)Bb * Nn * 4;     // raw sum-of-squares
  float* sqt   = (float*)ws; ws += (size_t)Bb * Mm * 4;
  float* scsh  = (float*)ws; ws += (size_t)Cch * 2 * 4;
  const int accN = 2 * Cch + Bb * Nn + Bb * Mm;             // 33280 floats

  zero_acc<<<(accN + 255) / 256, 256, 0, stream>>>(bnsum, accN);
  transpose_sq<<<dim3(Nn / 32, Cch / 32, Bb), dim3(32, 8), 0, stream>>>(x, xnT, xb, sqx);
  transpose_sq<<<dim3(Mm / 32, Cch / 32, Bb), dim3(32, 8), 0, stream>>>(tg, tgnT, nullptr, sqt);
  // E[b][m][n] = exp( dot(tg_m, x_n) * rsq(sqt[m]) * rsq(sqx[n]) )  (dbuf+XCD)
  gemm_bt1<<<dim3(Bb, (Mm / 128) * (Nn / 128), 1), 256, 0, stream>>>(tgnT, xnT, sqt, sqx, S, Mm, Nn, Cch);
  // in-place top-k mask on E + rowinv = 1/sum(E)
  row_topk_mask<<<Bb * Mm / 4, 256, 0, stream>>>(S, rowinv);
  // part[b][c][m] = sum_n xb[b][c][n] * Emask[b][m][n]  (wave-async)
  gemm2_wave<<<dim3(Bb, (Cch / 128) * (Mm / 64) * SPLITK2, 1), 256, 0, stream>>>(xb, S, part);
  combine_bn<<<Bb * Cch, 256, 0, stream>>>(part, rowinv, ybf, bnsum);
  bn_finalize<<<1, 256, 0, stream>>>(bnsum, bnw, bnb, scsh);
  final_kernel<<<2048, 256, 0, stream>>>(ybf, out, tg, scsh, gamma);
}